// Round 14
// baseline (25919.250 us; speedup 1.0000x reference)
//
#include <hip/hip_runtime.h>

#define Bb 512
#define Tt 512
#define Ll 256
#define Ff 256
#define Hh 128
#define H3 384
#define NZ 8
#define XC 16
#define OC 8
#define CF 9
#define W3N 1152
#define BBt 2     // batches per CDE block -> 256 blocks (1/CU)

__device__ __forceinline__ float sigm(float x){ return 1.0f/(1.0f+expf(-x)); }
__device__ __forceinline__ float softplus_(float x){
  return fmaxf(x, 0.0f) + log1pf(expf(-fabsf(x)));
}
__device__ __forceinline__ float dot4(float4 w, float4 z){
  return w.x*z.x + w.y*z.y + w.z*z.z + w.w*z.w;
}
// involutive float4-index swizzle for [32]-float4 state rows
__device__ __forceinline__ int swz32(int i){ return i ^ ((i >> 3) & 3); }
__device__ __forceinline__ int swzf(int h){ return (((h >> 2) ^ ((h >> 5) & 3)) << 2) + (h & 3); }
// butterfly add over lane bits 0..2: xor1,xor2 via DPP quad_perm (VALU),
// xor4 via ds_swizzle (DS). Sums the 8 lanes of an e8 group.
__device__ __forceinline__ float red8(float p){
  int t;
  t = __builtin_amdgcn_mov_dpp(__builtin_bit_cast(int, p), 0xB1, 0xF, 0xF, true); // quad_perm[1,0,3,2] = xor1
  p += __builtin_bit_cast(float, t);
  t = __builtin_amdgcn_mov_dpp(__builtin_bit_cast(int, p), 0x4E, 0xF, 0xF, true); // quad_perm[2,3,0,1] = xor2
  p += __builtin_bit_cast(float, t);
  t = __builtin_amdgcn_ds_swizzle(__builtin_bit_cast(int, p), 0x101F);            // xor4
  p += __builtin_bit_cast(float, t);
  return p;
}

// ---------------- GRU v3: 768 threads, 2/row, 1-step x-prefetch (unchanged) ---
__global__ __launch_bounds__(768) void gru_kernel(
    const float* __restrict__ xin, const float* __restrict__ zx_in,
    const float* __restrict__ tin,
    const float* __restrict__ wih, const float* __restrict__ whh,
    const float* __restrict__ bias, const float* __restrict__ bn,
    const float* __restrict__ zxlw, const float* __restrict__ zxlb,
    float* __restrict__ out_zx, float* __restrict__ out_h,
    int steps, int mode)
{
  const int b = blockIdx.x;
  const int tid = threadIdx.x;
  const int j = tid >> 1;
  const int half = tid & 1;

  float wi[17];
  #pragma unroll
  for (int c = 0; c < 17; c++) wi[c] = wih[j*17 + c];
  const float bj = bias[j];
  float4 wr[16];
  {
    const float4* p = reinterpret_cast<const float4*>(whh + (size_t)j*Hh + half*64);
    #pragma unroll
    for (int q = 0; q < 16; q++) wr[q] = p[q];
  }

  __shared__ __align__(16) float s_h[Hh];
  __shared__ float s_i[H3];
  __shared__ float s_g[H3];
  __shared__ float s_x[17];
  __shared__ float s_bn[Hh];
  __shared__ float s_zxlw[NZ*Hh];
  __shared__ float s_red[NZ][17];

  if (tid < Hh){ s_h[tid] = 0.0f; s_bn[tid] = bn[tid]; }
  if (mode == 0){ for (int q = tid; q < NZ*Hh; q += 768) s_zxlw[q] = zxlw[q]; }

  float xreg = 0.f;
  if (tid < 17){
    if (mode == 0){
      xreg = (tid < 16) ? xin[(size_t)b*Tt*XC + tid] : tin[0];
    } else {
      if (tid < 8)       xreg = xin[(size_t)b*Ll*NZ + tid];
      else if (tid < 16) xreg = zx_in[(size_t)b*Tt*NZ + (tid - 8)];
      else               xreg = tin[0];
    }
  }
  __syncthreads();

  for (int t = 0; t < steps; t++){
    if (tid < 17) s_x[tid] = xreg;
    __syncthreads();
    float ai = bj;
    #pragma unroll
    for (int c = 0; c < 17; c++) ai += wi[c]*s_x[c];
    float g0=0.f, g1=0.f, g2=0.f, g3=0.f;
    {
      const float4* h4p = reinterpret_cast<const float4*>(&s_h[half*64]);
      #pragma unroll
      for (int q = 0; q < 16; q++){
        float4 w = wr[q];
        float4 h4 = h4p[q];
        g0 += w.x*h4.x; g1 += w.y*h4.y; g2 += w.z*h4.z; g3 += w.w*h4.w;
      }
    }
    float g = (g0+g1)+(g2+g3);
    g += __shfl_xor(g, 1, 64);
    if (half == 0){ s_i[j] = ai; s_g[j] = g; }
    if (tid < 17 && t + 1 < steps){
      const int tn = t + 1;
      if (mode == 0){
        xreg = (tid < 16) ? xin[(size_t)b*Tt*XC + (size_t)tn*XC + tid] : tin[tn];
      } else {
        if (tid < 8)       xreg = xin[(size_t)b*Ll*NZ + (size_t)tn*NZ + tid];
        else if (tid < 16) xreg = zx_in[(size_t)b*Tt*NZ + (size_t)tn*NZ + (tid - 8)];
        else               xreg = tin[tn];
      }
    }
    __syncthreads();
    if (tid < Hh){
      float r  = sigm(s_i[tid]       + s_g[tid]);
      float zz = sigm(s_i[Hh + tid]  + s_g[Hh + tid]);
      float n  = tanhf(s_i[2*Hh+tid] + r*(s_g[2*Hh+tid] + s_bn[tid]));
      s_h[tid] = n + zz*(s_h[tid] - n);
    }
    __syncthreads();
    if (mode == 0){
      if (tid < Hh){
        int o = tid >> 4, m = tid & 15;
        float p = 0.f;
        #pragma unroll
        for (int q = 0; q < 8; q++) p += s_zxlw[o*Hh + m*8 + q]*s_h[m*8 + q];
        s_red[o][m] = p;
      }
      __syncthreads();
      if (tid < NZ){
        float p = zxlb[tid];
        #pragma unroll
        for (int m = 0; m < 16; m++) p += s_red[tid][m];
        out_zx[(size_t)b*Tt*NZ + (size_t)t*NZ + tid] = p;
      }
      __syncthreads();
    }
  }
  if (mode == 1 && tid < Hh) out_h[b*Hh + tid] = s_h[tid];
}

// ---------------- CDE RK4 v9 — 1024 threads, DPP reduces, e8 everywhere --------
// 256 blocks (1/CU) x 2 batches x 1024 threads (16 waves = 4/SIMD, cap 128).
// Per-thread shape identical to proven round-11 (2-deep x 4-float4 prefetch,
// ~92 VGPR); aggregate DS reduce work cut ~3x via DPP; 2x waves hide L2 latency.
__global__ __launch_bounds__(1024)
__attribute__((amdgpu_waves_per_eu(4, 4)))
void cde_fp32_kernel(
    const float* __restrict__ zy_h, const float* __restrict__ zx,
    const float* __restrict__ tin,
    const float* __restrict__ fw1, const float* __restrict__ fb1,
    const float* __restrict__ fw2, const float* __restrict__ fb2,
    const float* __restrict__ fw3, const float* __restrict__ fb3,
    const float* __restrict__ rw,  const float* __restrict__ rb,
    float* __restrict__ yout)
{
  const int tid = threadIdx.x;
  const int colG = tid >> 3;     // 0..127: G1/G2 output col; G3 col-in-group
  const int e8   = tid & 7;      // k-eighth (16 floats = 4 float4)
  const int bg = blockIdx.x * BBt;

  __shared__ __align__(16) float4 s_w1v[4096];   // 64 KB, [r][col*8+e8]
  __shared__ __align__(16) float4 s_w2v[4096];   // 64 KB
  __shared__ __align__(16) float4 s_zinv[BBt][32];  // swizzled state rows
  __shared__ __align__(16) float4 s_h1v[BBt][32];
  __shared__ __align__(16) float4 s_h2v[BBt][32];
  __shared__ float s_o[BBt][W3N];                // raw pre-activations
  __shared__ float s_z[BBt][Hh];
  __shared__ float s_kacc[BBt][Hh];
  __shared__ float s_dx[BBt][CF];
  __shared__ float s_rw[OC*Hh];
  __shared__ float s_rb[OC];
  __shared__ float s_b3[W3N];

  float* zin_f0 = reinterpret_cast<float*>(&s_zinv[0][0]);
  float* zin_f1 = reinterpret_cast<float*>(&s_zinv[1][0]);
  float* h1_f0  = reinterpret_cast<float*>(&s_h1v[0][0]);
  float* h1_f1  = reinterpret_cast<float*>(&s_h1v[1][0]);
  float* h2_f0  = reinterpret_cast<float*>(&s_h2v[0][0]);
  float* h2_f1  = reinterpret_cast<float*>(&s_h2v[1][0]);

  // ---- one-time: w1/w2 -> [r][col*8+e8] layout (read addr = r*1024+tid) ----
  for (int idx = tid; idx < Hh*32; idx += 1024){
    int col = idx >> 5, rem = idx & 31;
    int e = rem >> 2, r = rem & 3;
    int dst = r*1024 + col*8 + e;
    s_w1v[dst] = reinterpret_cast<const float4*>(fw1)[idx];
    s_w2v[dst] = reinterpret_cast<const float4*>(fw2)[idx];
  }
  const float b1r = fb1[colG], b2r = fb2[colG];
  for (int idx = tid; idx < W3N; idx += 1024) s_b3[idx] = fb3[idx];
  s_rw[tid] = rw[tid];                       // OC*Hh == 1024 exactly
  if (tid < OC) s_rb[tid] = rb[tid];
  if (tid < BBt*Hh){
    int b = tid >> 7, h = tid & 127;
    float zv = zy_h[(size_t)(bg + b)*Hh + h];
    s_z[b][h] = zv;
    (b == 0 ? zin_f0 : zin_f1)[swzf(h)] = zv;
  }
  __syncthreads();

  // y[:, 0, :]
  if (tid < 256){
    int b = tid >> 7, r = tid & 127, o = r >> 4, seg = r & 15;
    float p = 0.f;
    #pragma unroll
    for (int q = 0; q < 8; q++)
      p += s_z[b][seg*8 + q]*s_rw[o*Hh + seg*8 + q];
    p += __shfl_xor(p, 1, 64); p += __shfl_xor(p, 2, 64);
    p += __shfl_xor(p, 4, 64); p += __shfl_xor(p, 8, 64);
    if (seg == 0) yout[(size_t)(bg + b)*Ff*OC + o] = s_rb[o] + p;
  }

  // G3 stream base: row (g*128 + colG), k-range e8*16..+15
  const float* w3p = fw3 + (size_t)colG*Hh + e8*16;   // + g*16384 floats per iter

  for (int i = 0; i < Ff - 1; i++){
    if (tid < BBt*CF){
      int b = tid/CF, c = tid%CF;
      float d;
      if (c < 8){
        const float* zp = zx + (size_t)(bg + b)*Tt*NZ + (size_t)(Ll + i)*NZ + c;
        d = zp[NZ] - zp[0];
      } else {
        d = tin[Ll + i + 1] - tin[Ll + i];
      }
      s_dx[b][c] = d;
    }
    __syncthreads();

    for (int st = 0; st < 4; st++){
      // ---- issue w3 iters 0,1 now; latency hides under G1/G2 ----
      float4 A0, A1, A2, A3, B0, B1, B2, B3;
      {
        const float4* pA = reinterpret_cast<const float4*>(w3p);
        const float4* pB = reinterpret_cast<const float4*>(w3p + 16384);
        A0 = pA[0]; A1 = pA[1]; A2 = pA[2]; A3 = pA[3];
        B0 = pB[0]; B1 = pB[1]; B2 = pB[2]; B3 = pB[3];
      }
      // ---- G1: h1 = softplus(zin @ w1.T + b1) ----
      {
        float p0 = 0.f, p1 = 0.f;
        #pragma unroll
        for (int r = 0; r < 4; r++){
          float4 z0 = s_zinv[0][swz32(e8*4 + r)];
          float4 z1 = s_zinv[1][swz32(e8*4 + r)];
          float4 w = s_w1v[r*1024 + tid];
          p0 += dot4(w, z0); p1 += dot4(w, z1);
        }
        p0 = red8(p0); p1 = red8(p1);
        if (e8 == 0){
          h1_f0[swzf(colG)] = softplus_(b1r + p0);
          h1_f1[swzf(colG)] = softplus_(b1r + p1);
        }
      }
      __syncthreads();
      // ---- G2 ----
      {
        float p0 = 0.f, p1 = 0.f;
        #pragma unroll
        for (int r = 0; r < 4; r++){
          float4 z0 = s_h1v[0][swz32(e8*4 + r)];
          float4 z1 = s_h1v[1][swz32(e8*4 + r)];
          float4 w = s_w2v[r*1024 + tid];
          p0 += dot4(w, z0); p1 += dot4(w, z1);
        }
        p0 = red8(p0); p1 = red8(p1);
        if (e8 == 0){
          h2_f0[swzf(colG)] = softplus_(b2r + p0);
          h2_f1[swzf(colG)] = softplus_(b2r + p1);
        }
      }
      __syncthreads();
      // ---- G3: 9 iters of 128 cols; wide stream, A/B pipeline ----
      {
        float4 h2a0 = s_h2v[0][swz32(e8*4 + 0)];
        float4 h2a1 = s_h2v[0][swz32(e8*4 + 1)];
        float4 h2a2 = s_h2v[0][swz32(e8*4 + 2)];
        float4 h2a3 = s_h2v[0][swz32(e8*4 + 3)];
        float4 h2b0 = s_h2v[1][swz32(e8*4 + 0)];
        float4 h2b1 = s_h2v[1][swz32(e8*4 + 1)];
        float4 h2b2 = s_h2v[1][swz32(e8*4 + 2)];
        float4 h2b3 = s_h2v[1][swz32(e8*4 + 3)];
        #pragma unroll 2
        for (int g = 0; g < 9; g++){
          float4 c0, c1, c2, c3;
          if ((g & 1) == 0){
            c0 = A0; c1 = A1; c2 = A2; c3 = A3;
            if (g + 2 < 9){
              const float4* pF = reinterpret_cast<const float4*>(w3p + (size_t)(g+2)*16384);
              A0 = pF[0]; A1 = pF[1]; A2 = pF[2]; A3 = pF[3];
            }
          } else {
            c0 = B0; c1 = B1; c2 = B2; c3 = B3;
            if (g + 2 < 9){
              const float4* pF = reinterpret_cast<const float4*>(w3p + (size_t)(g+2)*16384);
              B0 = pF[0]; B1 = pF[1]; B2 = pF[2]; B3 = pF[3];
            }
          }
          float p0 = dot4(c0, h2a0) + dot4(c1, h2a1) + dot4(c2, h2a2) + dot4(c3, h2a3);
          float p1 = dot4(c0, h2b0) + dot4(c1, h2b1) + dot4(c2, h2b2) + dot4(c3, h2b3);
          p0 = red8(p0); p1 = red8(p1);
          if (e8 == 0){
            int n = g*128 + colG;
            s_o[0][n] = s_b3[n] + p0;
            s_o[1][n] = s_b3[n] + p1;
          }
        }
      }
      __syncthreads();
      // ---- phase B: k_h = sum_c tanh(raw)*dx + RK4 combine ----
      if (tid < BBt*Hh){
        int b = tid >> 7, h = tid & 127;
        float kc = 0.f;
        #pragma unroll
        for (int c = 0; c < CF; c++)
          kc += tanhf(s_o[b][h*CF + c]) * s_dx[b][c];
        float zv = s_z[b][h], zin;
        if      (st == 0){ s_kacc[b][h] = kc;        zin = zv + 0.5f*kc; }
        else if (st == 1){ s_kacc[b][h] += 2.f*kc;   zin = zv + 0.5f*kc; }
        else if (st == 2){ s_kacc[b][h] += 2.f*kc;   zin = zv + kc; }
        else { float zn = zv + (s_kacc[b][h] + kc)*(1.f/6.f); s_z[b][h] = zn; zin = zn; }
        (b == 0 ? zin_f0 : zin_f1)[swzf(h)] = zin;
      }
      __syncthreads();
    }
    // readout y[:, i+1, :]
    if (tid < 256){
      int b = tid >> 7, r = tid & 127, o = r >> 4, seg = r & 15;
      float p = 0.f;
      #pragma unroll
      for (int q = 0; q < 8; q++)
        p += s_z[b][seg*8 + q]*s_rw[o*Hh + seg*8 + q];
      p += __shfl_xor(p, 1, 64); p += __shfl_xor(p, 2, 64);
      p += __shfl_xor(p, 4, 64); p += __shfl_xor(p, 8, 64);
      if (seg == 0) yout[(size_t)(bg + b)*Ff*OC + (size_t)(i + 1)*OC + o] = s_rb[o] + p;
    }
  }
}

extern "C" void kernel_launch(void* const* d_in, const int* in_sizes, int n_in,
                              void* d_out, int out_size, void* d_ws, size_t ws_size,
                              hipStream_t stream)
{
  (void)in_sizes; (void)n_in; (void)out_size; (void)ws_size;
  const float* y_past = (const float*)d_in[0];
  const float* t_in   = (const float*)d_in[1];
  const float* coeffs = (const float*)d_in[2];
  // d_in[3] = input_length (fixed 256)
  const float* zx_wih = (const float*)d_in[4];
  const float* zx_whh = (const float*)d_in[5];
  const float* zx_b   = (const float*)d_in[6];
  const float* zx_bn  = (const float*)d_in[7];
  const float* zxl_w  = (const float*)d_in[8];
  const float* zxl_b  = (const float*)d_in[9];
  const float* zy_wih = (const float*)d_in[10];
  const float* zy_whh = (const float*)d_in[11];
  const float* zy_b   = (const float*)d_in[12];
  const float* zy_bn  = (const float*)d_in[13];
  const float* fw1 = (const float*)d_in[14];
  const float* fb1 = (const float*)d_in[15];
  const float* fw2 = (const float*)d_in[16];
  const float* fb2 = (const float*)d_in[17];
  const float* fw3 = (const float*)d_in[18];
  const float* fb3 = (const float*)d_in[19];
  const float* r_w = (const float*)d_in[20];
  const float* r_b = (const float*)d_in[21];

  float* ws = (float*)d_ws;
  float* zx_buf = ws;                              // B*T*NZ fp32 = 8.39 MB
  float* zy_buf = ws + (size_t)Bb*Tt*NZ;           // B*H fp32   = 256 KB

  gru_kernel<<<Bb, 768, 0, stream>>>(coeffs, nullptr, t_in,
                                     zx_wih, zx_whh, zx_b, zx_bn,
                                     zxl_w, zxl_b, zx_buf, nullptr, Tt, 0);
  gru_kernel<<<Bb, 768, 0, stream>>>(y_past, zx_buf, t_in,
                                     zy_wih, zy_whh, zy_b, zy_bn,
                                     nullptr, nullptr, nullptr, zy_buf, Ll, 1);
  cde_fp32_kernel<<<Bb/BBt, 1024, 0, stream>>>(zy_buf, zx_buf, t_in,
                                               fw1, fb1, fw2, fb2, fw3, fb3,
                                               r_w, r_b, (float*)d_out);
}

// Round 15
// 20959.361 us; speedup vs baseline: 1.2366x; 1.2366x over previous
//
#include <hip/hip_runtime.h>

#define Bb 512
#define Tt 512
#define Ll 256
#define Ff 256
#define Hh 128
#define H3 384
#define NZ 8
#define XC 16
#define OC 8
#define CF 9
#define W3N 1152
#define BBt 2     // batches per CDE block -> 256 blocks (1/CU)

__device__ __forceinline__ float sigm(float x){ return 1.0f/(1.0f+expf(-x)); }
__device__ __forceinline__ float softplus_(float x){
  return fmaxf(x, 0.0f) + log1pf(expf(-fabsf(x)));
}
__device__ __forceinline__ float tanh_fast(float x){   // phase-B only; |err|~1e-7
  float xc = fminf(fmaxf(x, -9.f), 9.f);
  float e = __expf(2.f*xc);
  return (e - 1.f)/(e + 1.f);
}
__device__ __forceinline__ float dot4(float4 w, float4 z){
  return w.x*z.x + w.y*z.y + w.z*z.z + w.w*z.w;
}
// involutive float4-index swizzle for [32]-float4 state rows
__device__ __forceinline__ int swz32(int i){ return i ^ ((i >> 3) & 3); }
__device__ __forceinline__ int swzf(int h){ return (((h >> 2) ^ ((h >> 5) & 3)) << 2) + (h & 3); }
// sum over lane bits 0..1 (q4 groups): pure-DPP butterfly (no DS)
__device__ __forceinline__ float red4(float p){
  int t;
  t = __builtin_amdgcn_mov_dpp(__builtin_bit_cast(int, p), 0xB1, 0xF, 0xF, true); // xor1
  p += __builtin_bit_cast(float, t);
  t = __builtin_amdgcn_mov_dpp(__builtin_bit_cast(int, p), 0x4E, 0xF, 0xF, true); // xor2
  p += __builtin_bit_cast(float, t);
  return p;
}
// sum over lane bits 0..2 (e8 groups): 2 DPP + 1 ds_swizzle
__device__ __forceinline__ float red8(float p){
  p = red4(p);
  int t = __builtin_amdgcn_ds_swizzle(__builtin_bit_cast(int, p), 0x101F);        // xor4
  p += __builtin_bit_cast(float, t);
  return p;
}

// ---------------- GRU v3: 768 threads, 2/row, 1-step x-prefetch (unchanged) ---
__global__ __launch_bounds__(768) void gru_kernel(
    const float* __restrict__ xin, const float* __restrict__ zx_in,
    const float* __restrict__ tin,
    const float* __restrict__ wih, const float* __restrict__ whh,
    const float* __restrict__ bias, const float* __restrict__ bn,
    const float* __restrict__ zxlw, const float* __restrict__ zxlb,
    float* __restrict__ out_zx, float* __restrict__ out_h,
    int steps, int mode)
{
  const int b = blockIdx.x;
  const int tid = threadIdx.x;
  const int j = tid >> 1;
  const int half = tid & 1;

  float wi[17];
  #pragma unroll
  for (int c = 0; c < 17; c++) wi[c] = wih[j*17 + c];
  const float bj = bias[j];
  float4 wr[16];
  {
    const float4* p = reinterpret_cast<const float4*>(whh + (size_t)j*Hh + half*64);
    #pragma unroll
    for (int q = 0; q < 16; q++) wr[q] = p[q];
  }

  __shared__ __align__(16) float s_h[Hh];
  __shared__ float s_i[H3];
  __shared__ float s_g[H3];
  __shared__ float s_x[17];
  __shared__ float s_bn[Hh];
  __shared__ float s_zxlw[NZ*Hh];
  __shared__ float s_red[NZ][17];

  if (tid < Hh){ s_h[tid] = 0.0f; s_bn[tid] = bn[tid]; }
  if (mode == 0){ for (int q = tid; q < NZ*Hh; q += 768) s_zxlw[q] = zxlw[q]; }

  float xreg = 0.f;
  if (tid < 17){
    if (mode == 0){
      xreg = (tid < 16) ? xin[(size_t)b*Tt*XC + tid] : tin[0];
    } else {
      if (tid < 8)       xreg = xin[(size_t)b*Ll*NZ + tid];
      else if (tid < 16) xreg = zx_in[(size_t)b*Tt*NZ + (tid - 8)];
      else               xreg = tin[0];
    }
  }
  __syncthreads();

  for (int t = 0; t < steps; t++){
    if (tid < 17) s_x[tid] = xreg;
    __syncthreads();
    float ai = bj;
    #pragma unroll
    for (int c = 0; c < 17; c++) ai += wi[c]*s_x[c];
    float g0=0.f, g1=0.f, g2=0.f, g3=0.f;
    {
      const float4* h4p = reinterpret_cast<const float4*>(&s_h[half*64]);
      #pragma unroll
      for (int q = 0; q < 16; q++){
        float4 w = wr[q];
        float4 h4 = h4p[q];
        g0 += w.x*h4.x; g1 += w.y*h4.y; g2 += w.z*h4.z; g3 += w.w*h4.w;
      }
    }
    float g = (g0+g1)+(g2+g3);
    g += __shfl_xor(g, 1, 64);
    if (half == 0){ s_i[j] = ai; s_g[j] = g; }
    if (tid < 17 && t + 1 < steps){
      const int tn = t + 1;
      if (mode == 0){
        xreg = (tid < 16) ? xin[(size_t)b*Tt*XC + (size_t)tn*XC + tid] : tin[tn];
      } else {
        if (tid < 8)       xreg = xin[(size_t)b*Ll*NZ + (size_t)tn*NZ + tid];
        else if (tid < 16) xreg = zx_in[(size_t)b*Tt*NZ + (size_t)tn*NZ + (tid - 8)];
        else               xreg = tin[tn];
      }
    }
    __syncthreads();
    if (tid < Hh){
      float r  = sigm(s_i[tid]       + s_g[tid]);
      float zz = sigm(s_i[Hh + tid]  + s_g[Hh + tid]);
      float n  = tanhf(s_i[2*Hh+tid] + r*(s_g[2*Hh+tid] + s_bn[tid]));
      s_h[tid] = n + zz*(s_h[tid] - n);
    }
    __syncthreads();
    if (mode == 0){
      if (tid < Hh){
        int o = tid >> 4, m = tid & 15;
        float p = 0.f;
        #pragma unroll
        for (int q = 0; q < 8; q++) p += s_zxlw[o*Hh + m*8 + q]*s_h[m*8 + q];
        s_red[o][m] = p;
      }
      __syncthreads();
      if (tid < NZ){
        float p = zxlb[tid];
        #pragma unroll
        for (int m = 0; m < 16; m++) p += s_red[tid][m];
        out_zx[(size_t)b*Tt*NZ + (size_t)t*NZ + tid] = p;
      }
      __syncthreads();
    }
  }
  if (mode == 1 && tid < Hh) out_h[b*Hh + tid] = s_h[tid];
}

// ---------------- CDE RK4 v10 — round-13 base + DPP reduces + 3-deep G3 -------
// 256 blocks (1/CU) x 2 batches x 512 threads (proven allocator-safe shape).
__global__ __launch_bounds__(512)
__attribute__((amdgpu_waves_per_eu(2, 2)))
void cde_fp32_kernel(
    const float* __restrict__ zy_h, const float* __restrict__ zx,
    const float* __restrict__ tin,
    const float* __restrict__ fw1, const float* __restrict__ fb1,
    const float* __restrict__ fw2, const float* __restrict__ fb2,
    const float* __restrict__ fw3, const float* __restrict__ fb3,
    const float* __restrict__ rw,  const float* __restrict__ rb,
    float* __restrict__ yout)
{
  const int tid = threadIdx.x;
  const int c12 = tid >> 2;      // G1/G2: output col 0..127
  const int q4  = tid & 3;       // G1/G2: k-quarter
  const int col64 = tid >> 3;    // G3: col-in-group 0..63
  const int e8    = tid & 7;     // G3: k-eighth (16 floats)
  const int bg = blockIdx.x * BBt;

  __shared__ __align__(16) float4 s_w1v[4096];   // 64 KB, [jj][col*4+q4]
  __shared__ __align__(16) float4 s_w2v[4096];   // 64 KB
  __shared__ __align__(16) float4 s_zinv[BBt][32];  // swizzled state rows
  __shared__ __align__(16) float4 s_h1v[BBt][32];
  __shared__ __align__(16) float4 s_h2v[BBt][32];
  __shared__ float s_o[BBt][W3N];                // raw pre-activations
  __shared__ float s_z[BBt][Hh];
  __shared__ float s_kacc[BBt][Hh];
  __shared__ float s_dx[BBt][CF];
  __shared__ float s_rw[OC*Hh];
  __shared__ float s_rb[OC];
  __shared__ float s_b3[W3N];

  float* zin_f0 = reinterpret_cast<float*>(&s_zinv[0][0]);
  float* zin_f1 = reinterpret_cast<float*>(&s_zinv[1][0]);
  float* h1_f0  = reinterpret_cast<float*>(&s_h1v[0][0]);
  float* h1_f1  = reinterpret_cast<float*>(&s_h1v[1][0]);
  float* h2_f0  = reinterpret_cast<float*>(&s_h2v[0][0]);
  float* h2_f1  = reinterpret_cast<float*>(&s_h2v[1][0]);

  // ---- one-time: w1/w2 -> [jj][col*4+q] layout; biases, readout, init ----
  for (int idx = tid; idx < Hh*32; idx += 512){
    int col = idx >> 5, jcol = idx & 31;
    int q = jcol >> 3, jj = jcol & 7;
    int dst = jj*512 + col*4 + q;
    s_w1v[dst] = reinterpret_cast<const float4*>(fw1)[idx];
    s_w2v[dst] = reinterpret_cast<const float4*>(fw2)[idx];
  }
  const float b1r = fb1[c12], b2r = fb2[c12];
  for (int idx = tid; idx < W3N; idx += 512) s_b3[idx] = fb3[idx];
  for (int idx = tid; idx < OC*Hh; idx += 512) s_rw[idx] = rw[idx];
  if (tid < OC) s_rb[tid] = rb[tid];
  if (tid < BBt*Hh){
    int b = tid >> 7, h = tid & 127;
    float zv = zy_h[(size_t)(bg + b)*Hh + h];
    s_z[b][h] = zv;
    (b == 0 ? zin_f0 : zin_f1)[swzf(h)] = zv;
  }
  __syncthreads();

  // y[:, 0, :]
  if (tid < 256){
    int b = tid >> 7, r = tid & 127, o = r >> 4, seg = r & 15;
    float p = 0.f;
    #pragma unroll
    for (int q = 0; q < 8; q++)
      p += s_z[b][seg*8 + q]*s_rw[o*Hh + seg*8 + q];
    p += __shfl_xor(p, 1, 64); p += __shfl_xor(p, 2, 64);
    p += __shfl_xor(p, 4, 64); p += __shfl_xor(p, 8, 64);
    if (seg == 0) yout[(size_t)(bg + b)*Ff*OC + o] = s_rb[o] + p;
  }

  const float* w3p = fw3 + (size_t)col64*Hh + e8*16;   // + g*8192 floats per iter

  for (int i = 0; i < Ff - 1; i++){
    if (tid < BBt*CF){
      int b = tid/CF, c = tid%CF;
      float d;
      if (c < 8){
        const float* zp = zx + (size_t)(bg + b)*Tt*NZ + (size_t)(Ll + i)*NZ + c;
        d = zp[NZ] - zp[0];
      } else {
        d = tin[Ll + i + 1] - tin[Ll + i];
      }
      s_dx[b][c] = d;
    }
    __syncthreads();

    for (int st = 0; st < 4; st++){
      // ---- issue w3 iters 0,1,2 now; latency hides under G1/G2 ----
      float4 A0, A1, A2, A3, B0, B1, B2, B3, C0, C1, C2, C3;
      {
        const float4* pA = reinterpret_cast<const float4*>(w3p);
        const float4* pB = reinterpret_cast<const float4*>(w3p + 8192);
        const float4* pC = reinterpret_cast<const float4*>(w3p + 2*8192);
        A0 = pA[0]; A1 = pA[1]; A2 = pA[2]; A3 = pA[3];
        B0 = pB[0]; B1 = pB[1]; B2 = pB[2]; B3 = pB[3];
        C0 = pC[0]; C1 = pC[1]; C2 = pC[2]; C3 = pC[3];
      }
      // ---- G1: h1 = softplus(zin @ w1.T + b1); DPP reduce (no DS) ----
      {
        float p0 = 0.f, p1 = 0.f;
        #pragma unroll
        for (int jj = 0; jj < 8; jj++){
          float4 z0 = s_zinv[0][swz32(q4*8 + jj)];
          float4 z1 = s_zinv[1][swz32(q4*8 + jj)];
          float4 w = s_w1v[jj*512 + tid];
          p0 += dot4(w, z0); p1 += dot4(w, z1);
        }
        p0 = red4(p0); p1 = red4(p1);
        if (q4 == 0){
          h1_f0[swzf(c12)] = softplus_(b1r + p0);
          h1_f1[swzf(c12)] = softplus_(b1r + p1);
        }
      }
      __syncthreads();
      // ---- G2 ----
      {
        float p0 = 0.f, p1 = 0.f;
        #pragma unroll
        for (int jj = 0; jj < 8; jj++){
          float4 z0 = s_h1v[0][swz32(q4*8 + jj)];
          float4 z1 = s_h1v[1][swz32(q4*8 + jj)];
          float4 w = s_w2v[jj*512 + tid];
          p0 += dot4(w, z0); p1 += dot4(w, z1);
        }
        p0 = red4(p0); p1 = red4(p1);
        if (q4 == 0){
          h2_f0[swzf(c12)] = softplus_(b2r + p0);
          h2_f1[swzf(c12)] = softplus_(b2r + p1);
        }
      }
      __syncthreads();
      // ---- G3: 18 iters, 3-deep A/B/C pipeline, red8 (2 DPP + 1 DS) ----
      {
        float4 h2a0 = s_h2v[0][swz32(e8*4 + 0)];
        float4 h2a1 = s_h2v[0][swz32(e8*4 + 1)];
        float4 h2a2 = s_h2v[0][swz32(e8*4 + 2)];
        float4 h2a3 = s_h2v[0][swz32(e8*4 + 3)];
        float4 h2b0 = s_h2v[1][swz32(e8*4 + 0)];
        float4 h2b1 = s_h2v[1][swz32(e8*4 + 1)];
        float4 h2b2 = s_h2v[1][swz32(e8*4 + 2)];
        float4 h2b3 = s_h2v[1][swz32(e8*4 + 3)];
        #pragma unroll
        for (int g = 0; g < 18; g++){
          float4 c0, c1, c2, c3;
          const int sl = g % 3;               // constant after full unroll
          if (sl == 0){
            c0 = A0; c1 = A1; c2 = A2; c3 = A3;
            if (g + 3 < 18){
              const float4* pF = reinterpret_cast<const float4*>(w3p + (size_t)(g+3)*8192);
              A0 = pF[0]; A1 = pF[1]; A2 = pF[2]; A3 = pF[3];
            }
          } else if (sl == 1){
            c0 = B0; c1 = B1; c2 = B2; c3 = B3;
            if (g + 3 < 18){
              const float4* pF = reinterpret_cast<const float4*>(w3p + (size_t)(g+3)*8192);
              B0 = pF[0]; B1 = pF[1]; B2 = pF[2]; B3 = pF[3];
            }
          } else {
            c0 = C0; c1 = C1; c2 = C2; c3 = C3;
            if (g + 3 < 18){
              const float4* pF = reinterpret_cast<const float4*>(w3p + (size_t)(g+3)*8192);
              C0 = pF[0]; C1 = pF[1]; C2 = pF[2]; C3 = pF[3];
            }
          }
          float p0 = dot4(c0, h2a0) + dot4(c1, h2a1) + dot4(c2, h2a2) + dot4(c3, h2a3);
          float p1 = dot4(c0, h2b0) + dot4(c1, h2b1) + dot4(c2, h2b2) + dot4(c3, h2b3);
          p0 = red8(p0); p1 = red8(p1);
          if (e8 == 0){
            int n = g*64 + col64;
            s_o[0][n] = s_b3[n] + p0;
            s_o[1][n] = s_b3[n] + p1;
          }
        }
      }
      __syncthreads();
      // ---- phase B: k_h = sum_c tanh(raw)*dx + RK4 combine ----
      if (tid < BBt*Hh){
        int b = tid >> 7, h = tid & 127;
        float kc = 0.f;
        #pragma unroll
        for (int c = 0; c < CF; c++)
          kc += tanh_fast(s_o[b][h*CF + c]) * s_dx[b][c];
        float zv = s_z[b][h], zin;
        if      (st == 0){ s_kacc[b][h] = kc;        zin = zv + 0.5f*kc; }
        else if (st == 1){ s_kacc[b][h] += 2.f*kc;   zin = zv + 0.5f*kc; }
        else if (st == 2){ s_kacc[b][h] += 2.f*kc;   zin = zv + kc; }
        else { float zn = zv + (s_kacc[b][h] + kc)*(1.f/6.f); s_z[b][h] = zn; zin = zn; }
        (b == 0 ? zin_f0 : zin_f1)[swzf(h)] = zin;
      }
      __syncthreads();
    }
    // readout y[:, i+1, :]
    if (tid < 256){
      int b = tid >> 7, r = tid & 127, o = r >> 4, seg = r & 15;
      float p = 0.f;
      #pragma unroll
      for (int q = 0; q < 8; q++)
        p += s_z[b][seg*8 + q]*s_rw[o*Hh + seg*8 + q];
      p += __shfl_xor(p, 1, 64); p += __shfl_xor(p, 2, 64);
      p += __shfl_xor(p, 4, 64); p += __shfl_xor(p, 8, 64);
      if (seg == 0) yout[(size_t)(bg + b)*Ff*OC + (size_t)(i + 1)*OC + o] = s_rb[o] + p;
    }
  }
}

extern "C" void kernel_launch(void* const* d_in, const int* in_sizes, int n_in,
                              void* d_out, int out_size, void* d_ws, size_t ws_size,
                              hipStream_t stream)
{
  (void)in_sizes; (void)n_in; (void)out_size; (void)ws_size;
  const float* y_past = (const float*)d_in[0];
  const float* t_in   = (const float*)d_in[1];
  const float* coeffs = (const float*)d_in[2];
  // d_in[3] = input_length (fixed 256)
  const float* zx_wih = (const float*)d_in[4];
  const float* zx_whh = (const float*)d_in[5];
  const float* zx_b   = (const float*)d_in[6];
  const float* zx_bn  = (const float*)d_in[7];
  const float* zxl_w  = (const float*)d_in[8];
  const float* zxl_b  = (const float*)d_in[9];
  const float* zy_wih = (const float*)d_in[10];
  const float* zy_whh = (const float*)d_in[11];
  const float* zy_b   = (const float*)d_in[12];
  const float* zy_bn  = (const float*)d_in[13];
  const float* fw1 = (const float*)d_in[14];
  const float* fb1 = (const float*)d_in[15];
  const float* fw2 = (const float*)d_in[16];
  const float* fb2 = (const float*)d_in[17];
  const float* fw3 = (const float*)d_in[18];
  const float* fb3 = (const float*)d_in[19];
  const float* r_w = (const float*)d_in[20];
  const float* r_b = (const float*)d_in[21];

  float* ws = (float*)d_ws;
  float* zx_buf = ws;                              // B*T*NZ fp32 = 8.39 MB
  float* zy_buf = ws + (size_t)Bb*Tt*NZ;           // B*H fp32   = 256 KB

  gru_kernel<<<Bb, 768, 0, stream>>>(coeffs, nullptr, t_in,
                                     zx_wih, zx_whh, zx_b, zx_bn,
                                     zxl_w, zxl_b, zx_buf, nullptr, Tt, 0);
  gru_kernel<<<Bb, 768, 0, stream>>>(y_past, zx_buf, t_in,
                                     zy_wih, zy_whh, zy_b, zy_bn,
                                     nullptr, nullptr, nullptr, zy_buf, Ll, 1);
  cde_fp32_kernel<<<Bb/BBt, 512, 0, stream>>>(zy_buf, zx_buf, t_in,
                                              fw1, fb1, fw2, fb2, fw3, fb3,
                                              r_w, r_b, (float*)d_out);
}

// Round 16
// 13543.332 us; speedup vs baseline: 1.9138x; 1.5476x over previous
//
#include <hip/hip_runtime.h>

#define Bb 512
#define Tt 512
#define Ll 256
#define Ff 256
#define Hh 128
#define H3 384
#define NZ 8
#define XC 16
#define OC 8
#define CF 9
#define W3N 1152
#define BBt 2     // batches per CDE block -> 256 blocks (1/CU)

__device__ __forceinline__ float sigm(float x){ return 1.0f/(1.0f+expf(-x)); }
__device__ __forceinline__ float softplus_(float x){
  return fmaxf(x, 0.0f) + log1pf(expf(-fabsf(x)));
}
__device__ __forceinline__ float tanh_fast(float x){   // phase-B only; |err|~1e-7
  float xc = fminf(fmaxf(x, -9.f), 9.f);
  float e = __expf(2.f*xc);
  return (e - 1.f)/(e + 1.f);
}
__device__ __forceinline__ float dot4(float4 w, float4 z){
  return w.x*z.x + w.y*z.y + w.z*z.z + w.w*z.w;
}
// involutive float4-index swizzle for [32]-float4 state rows
__device__ __forceinline__ int swz32(int i){ return i ^ ((i >> 3) & 3); }
__device__ __forceinline__ int swzf(int h){ return (((h >> 2) ^ ((h >> 5) & 3)) << 2) + (h & 3); }
// sum over lane bits 0..1 (q4 groups): pure-DPP butterfly (no DS) [HW-proven r15]
__device__ __forceinline__ float red4(float p){
  int t;
  t = __builtin_amdgcn_mov_dpp(__builtin_bit_cast(int, p), 0xB1, 0xF, 0xF, true); // xor1
  p += __builtin_bit_cast(float, t);
  t = __builtin_amdgcn_mov_dpp(__builtin_bit_cast(int, p), 0x4E, 0xF, 0xF, true); // xor2
  p += __builtin_bit_cast(float, t);
  return p;
}
// sum over lane bits 0..2 (e8 groups): 2 DPP + 1 ds_swizzle [HW-proven r15]
__device__ __forceinline__ float red8(float p){
  p = red4(p);
  int t = __builtin_amdgcn_ds_swizzle(__builtin_bit_cast(int, p), 0x101F);        // xor4
  p += __builtin_bit_cast(float, t);
  return p;
}

// ---------------- GRU v3: 768 threads, 2/row, 1-step x-prefetch (unchanged) ---
__global__ __launch_bounds__(768) void gru_kernel(
    const float* __restrict__ xin, const float* __restrict__ zx_in,
    const float* __restrict__ tin,
    const float* __restrict__ wih, const float* __restrict__ whh,
    const float* __restrict__ bias, const float* __restrict__ bn,
    const float* __restrict__ zxlw, const float* __restrict__ zxlb,
    float* __restrict__ out_zx, float* __restrict__ out_h,
    int steps, int mode)
{
  const int b = blockIdx.x;
  const int tid = threadIdx.x;
  const int j = tid >> 1;
  const int half = tid & 1;

  float wi[17];
  #pragma unroll
  for (int c = 0; c < 17; c++) wi[c] = wih[j*17 + c];
  const float bj = bias[j];
  float4 wr[16];
  {
    const float4* p = reinterpret_cast<const float4*>(whh + (size_t)j*Hh + half*64);
    #pragma unroll
    for (int q = 0; q < 16; q++) wr[q] = p[q];
  }

  __shared__ __align__(16) float s_h[Hh];
  __shared__ float s_i[H3];
  __shared__ float s_g[H3];
  __shared__ float s_x[17];
  __shared__ float s_bn[Hh];
  __shared__ float s_zxlw[NZ*Hh];
  __shared__ float s_red[NZ][17];

  if (tid < Hh){ s_h[tid] = 0.0f; s_bn[tid] = bn[tid]; }
  if (mode == 0){ for (int q = tid; q < NZ*Hh; q += 768) s_zxlw[q] = zxlw[q]; }

  float xreg = 0.f;
  if (tid < 17){
    if (mode == 0){
      xreg = (tid < 16) ? xin[(size_t)b*Tt*XC + tid] : tin[0];
    } else {
      if (tid < 8)       xreg = xin[(size_t)b*Ll*NZ + tid];
      else if (tid < 16) xreg = zx_in[(size_t)b*Tt*NZ + (tid - 8)];
      else               xreg = tin[0];
    }
  }
  __syncthreads();

  for (int t = 0; t < steps; t++){
    if (tid < 17) s_x[tid] = xreg;
    __syncthreads();
    float ai = bj;
    #pragma unroll
    for (int c = 0; c < 17; c++) ai += wi[c]*s_x[c];
    float g0=0.f, g1=0.f, g2=0.f, g3=0.f;
    {
      const float4* h4p = reinterpret_cast<const float4*>(&s_h[half*64]);
      #pragma unroll
      for (int q = 0; q < 16; q++){
        float4 w = wr[q];
        float4 h4 = h4p[q];
        g0 += w.x*h4.x; g1 += w.y*h4.y; g2 += w.z*h4.z; g3 += w.w*h4.w;
      }
    }
    float g = (g0+g1)+(g2+g3);
    g += __shfl_xor(g, 1, 64);
    if (half == 0){ s_i[j] = ai; s_g[j] = g; }
    if (tid < 17 && t + 1 < steps){
      const int tn = t + 1;
      if (mode == 0){
        xreg = (tid < 16) ? xin[(size_t)b*Tt*XC + (size_t)tn*XC + tid] : tin[tn];
      } else {
        if (tid < 8)       xreg = xin[(size_t)b*Ll*NZ + (size_t)tn*NZ + tid];
        else if (tid < 16) xreg = zx_in[(size_t)b*Tt*NZ + (size_t)tn*NZ + (tid - 8)];
        else               xreg = tin[tn];
      }
    }
    __syncthreads();
    if (tid < Hh){
      float r  = sigm(s_i[tid]       + s_g[tid]);
      float zz = sigm(s_i[Hh + tid]  + s_g[Hh + tid]);
      float n  = tanhf(s_i[2*Hh+tid] + r*(s_g[2*Hh+tid] + s_bn[tid]));
      s_h[tid] = n + zz*(s_h[tid] - n);
    }
    __syncthreads();
    if (mode == 0){
      if (tid < Hh){
        int o = tid >> 4, m = tid & 15;
        float p = 0.f;
        #pragma unroll
        for (int q = 0; q < 8; q++) p += s_zxlw[o*Hh + m*8 + q]*s_h[m*8 + q];
        s_red[o][m] = p;
      }
      __syncthreads();
      if (tid < NZ){
        float p = zxlb[tid];
        #pragma unroll
        for (int m = 0; m < 16; m++) p += s_red[tid][m];
        out_zx[(size_t)b*Tt*NZ + (size_t)t*NZ + tid] = p;
      }
      __syncthreads();
    }
  }
  if (mode == 1 && tid < Hh) out_h[b*Hh + tid] = s_h[tid];
}

// ---------------- CDE RK4 v11 — round-13 shape (2-deep, 92 VGPR) + DPP --------
// 256 blocks (1/CU) x 2 batches x 512 threads. The allocator-safe config:
// any per-lane live set past ~100 VGPR spills (r12/r14/r15 evidence).
__global__ __launch_bounds__(512)
__attribute__((amdgpu_waves_per_eu(2, 2)))
void cde_fp32_kernel(
    const float* __restrict__ zy_h, const float* __restrict__ zx,
    const float* __restrict__ tin,
    const float* __restrict__ fw1, const float* __restrict__ fb1,
    const float* __restrict__ fw2, const float* __restrict__ fb2,
    const float* __restrict__ fw3, const float* __restrict__ fb3,
    const float* __restrict__ rw,  const float* __restrict__ rb,
    float* __restrict__ yout)
{
  const int tid = threadIdx.x;
  const int c12 = tid >> 2;      // G1/G2: output col 0..127
  const int q4  = tid & 3;       // G1/G2: k-quarter
  const int col64 = tid >> 3;    // G3: col-in-group 0..63
  const int e8    = tid & 7;     // G3: k-eighth (16 floats)
  const int bg = blockIdx.x * BBt;

  __shared__ __align__(16) float4 s_w1v[4096];   // 64 KB, [jj][col*4+q4]
  __shared__ __align__(16) float4 s_w2v[4096];   // 64 KB
  __shared__ __align__(16) float4 s_zinv[BBt][32];  // swizzled state rows
  __shared__ __align__(16) float4 s_h1v[BBt][32];
  __shared__ __align__(16) float4 s_h2v[BBt][32];
  __shared__ float s_o[BBt][W3N];                // raw pre-activations
  __shared__ float s_z[BBt][Hh];
  __shared__ float s_kacc[BBt][Hh];
  __shared__ float s_dx[BBt][CF];
  __shared__ float s_rw[OC*Hh];
  __shared__ float s_rb[OC];
  __shared__ float s_b3[W3N];

  float* zin_f0 = reinterpret_cast<float*>(&s_zinv[0][0]);
  float* zin_f1 = reinterpret_cast<float*>(&s_zinv[1][0]);
  float* h1_f0  = reinterpret_cast<float*>(&s_h1v[0][0]);
  float* h1_f1  = reinterpret_cast<float*>(&s_h1v[1][0]);
  float* h2_f0  = reinterpret_cast<float*>(&s_h2v[0][0]);
  float* h2_f1  = reinterpret_cast<float*>(&s_h2v[1][0]);

  // ---- one-time: w1/w2 -> [jj][col*4+q] layout; biases, readout, init ----
  for (int idx = tid; idx < Hh*32; idx += 512){
    int col = idx >> 5, jcol = idx & 31;
    int q = jcol >> 3, jj = jcol & 7;
    int dst = jj*512 + col*4 + q;
    s_w1v[dst] = reinterpret_cast<const float4*>(fw1)[idx];
    s_w2v[dst] = reinterpret_cast<const float4*>(fw2)[idx];
  }
  const float b1r = fb1[c12], b2r = fb2[c12];
  for (int idx = tid; idx < W3N; idx += 512) s_b3[idx] = fb3[idx];
  for (int idx = tid; idx < OC*Hh; idx += 512) s_rw[idx] = rw[idx];
  if (tid < OC) s_rb[tid] = rb[tid];
  if (tid < BBt*Hh){
    int b = tid >> 7, h = tid & 127;
    float zv = zy_h[(size_t)(bg + b)*Hh + h];
    s_z[b][h] = zv;
    (b == 0 ? zin_f0 : zin_f1)[swzf(h)] = zv;
  }
  __syncthreads();

  // y[:, 0, :]
  if (tid < 256){
    int b = tid >> 7, r = tid & 127, o = r >> 4, seg = r & 15;
    float p = 0.f;
    #pragma unroll
    for (int q = 0; q < 8; q++)
      p += s_z[b][seg*8 + q]*s_rw[o*Hh + seg*8 + q];
    p += __shfl_xor(p, 1, 64); p += __shfl_xor(p, 2, 64);
    p += __shfl_xor(p, 4, 64); p += __shfl_xor(p, 8, 64);
    if (seg == 0) yout[(size_t)(bg + b)*Ff*OC + o] = s_rb[o] + p;
  }

  const float* w3p = fw3 + (size_t)col64*Hh + e8*16;   // + g*8192 floats per iter

  for (int i = 0; i < Ff - 1; i++){
    if (tid < BBt*CF){
      int b = tid/CF, c = tid%CF;
      float d;
      if (c < 8){
        const float* zp = zx + (size_t)(bg + b)*Tt*NZ + (size_t)(Ll + i)*NZ + c;
        d = zp[NZ] - zp[0];
      } else {
        d = tin[Ll + i + 1] - tin[Ll + i];
      }
      s_dx[b][c] = d;
    }
    __syncthreads();

    for (int st = 0; st < 4; st++){
      // ---- issue w3 iters 0,1 now; latency hides under G1/G2 (2-deep only!) ----
      float4 A0, A1, A2, A3, B0, B1, B2, B3;
      {
        const float4* pA = reinterpret_cast<const float4*>(w3p);
        const float4* pB = reinterpret_cast<const float4*>(w3p + 8192);
        A0 = pA[0]; A1 = pA[1]; A2 = pA[2]; A3 = pA[3];
        B0 = pB[0]; B1 = pB[1]; B2 = pB[2]; B3 = pB[3];
      }
      // ---- G1: h1 = softplus(zin @ w1.T + b1); DPP reduce (no DS) ----
      {
        float p0 = 0.f, p1 = 0.f;
        #pragma unroll
        for (int jj = 0; jj < 8; jj++){
          float4 z0 = s_zinv[0][swz32(q4*8 + jj)];
          float4 z1 = s_zinv[1][swz32(q4*8 + jj)];
          float4 w = s_w1v[jj*512 + tid];
          p0 += dot4(w, z0); p1 += dot4(w, z1);
        }
        p0 = red4(p0); p1 = red4(p1);
        if (q4 == 0){
          h1_f0[swzf(c12)] = softplus_(b1r + p0);
          h1_f1[swzf(c12)] = softplus_(b1r + p1);
        }
      }
      __syncthreads();
      // ---- G2 ----
      {
        float p0 = 0.f, p1 = 0.f;
        #pragma unroll
        for (int jj = 0; jj < 8; jj++){
          float4 z0 = s_h1v[0][swz32(q4*8 + jj)];
          float4 z1 = s_h1v[1][swz32(q4*8 + jj)];
          float4 w = s_w2v[jj*512 + tid];
          p0 += dot4(w, z0); p1 += dot4(w, z1);
        }
        p0 = red4(p0); p1 = red4(p1);
        if (q4 == 0){
          h2_f0[swzf(c12)] = softplus_(b2r + p0);
          h2_f1[swzf(c12)] = softplus_(b2r + p1);
        }
      }
      __syncthreads();
      // ---- G3: 18 iters, 2-deep A/B pipeline, red8 (2 DPP + 1 DS) ----
      {
        float4 h2a0 = s_h2v[0][swz32(e8*4 + 0)];
        float4 h2a1 = s_h2v[0][swz32(e8*4 + 1)];
        float4 h2a2 = s_h2v[0][swz32(e8*4 + 2)];
        float4 h2a3 = s_h2v[0][swz32(e8*4 + 3)];
        float4 h2b0 = s_h2v[1][swz32(e8*4 + 0)];
        float4 h2b1 = s_h2v[1][swz32(e8*4 + 1)];
        float4 h2b2 = s_h2v[1][swz32(e8*4 + 2)];
        float4 h2b3 = s_h2v[1][swz32(e8*4 + 3)];
        #pragma unroll 2
        for (int g = 0; g < 18; g++){
          float4 c0, c1, c2, c3;
          if ((g & 1) == 0){
            c0 = A0; c1 = A1; c2 = A2; c3 = A3;
            if (g + 2 < 18){
              const float4* pF = reinterpret_cast<const float4*>(w3p + (size_t)(g+2)*8192);
              A0 = pF[0]; A1 = pF[1]; A2 = pF[2]; A3 = pF[3];
            }
          } else {
            c0 = B0; c1 = B1; c2 = B2; c3 = B3;
            if (g + 2 < 18){
              const float4* pF = reinterpret_cast<const float4*>(w3p + (size_t)(g+2)*8192);
              B0 = pF[0]; B1 = pF[1]; B2 = pF[2]; B3 = pF[3];
            }
          }
          float p0 = dot4(c0, h2a0) + dot4(c1, h2a1) + dot4(c2, h2a2) + dot4(c3, h2a3);
          float p1 = dot4(c0, h2b0) + dot4(c1, h2b1) + dot4(c2, h2b2) + dot4(c3, h2b3);
          p0 = red8(p0); p1 = red8(p1);
          if (e8 == 0){
            int n = g*64 + col64;
            s_o[0][n] = s_b3[n] + p0;
            s_o[1][n] = s_b3[n] + p1;
          }
        }
      }
      __syncthreads();
      // ---- phase B: k_h = sum_c tanh(raw)*dx + RK4 combine ----
      if (tid < BBt*Hh){
        int b = tid >> 7, h = tid & 127;
        float kc = 0.f;
        #pragma unroll
        for (int c = 0; c < CF; c++)
          kc += tanh_fast(s_o[b][h*CF + c]) * s_dx[b][c];
        float zv = s_z[b][h], zin;
        if      (st == 0){ s_kacc[b][h] = kc;        zin = zv + 0.5f*kc; }
        else if (st == 1){ s_kacc[b][h] += 2.f*kc;   zin = zv + 0.5f*kc; }
        else if (st == 2){ s_kacc[b][h] += 2.f*kc;   zin = zv + kc; }
        else { float zn = zv + (s_kacc[b][h] + kc)*(1.f/6.f); s_z[b][h] = zn; zin = zn; }
        (b == 0 ? zin_f0 : zin_f1)[swzf(h)] = zin;
      }
      __syncthreads();
    }
    // readout y[:, i+1, :]
    if (tid < 256){
      int b = tid >> 7, r = tid & 127, o = r >> 4, seg = r & 15;
      float p = 0.f;
      #pragma unroll
      for (int q = 0; q < 8; q++)
        p += s_z[b][seg*8 + q]*s_rw[o*Hh + seg*8 + q];
      p += __shfl_xor(p, 1, 64); p += __shfl_xor(p, 2, 64);
      p += __shfl_xor(p, 4, 64); p += __shfl_xor(p, 8, 64);
      if (seg == 0) yout[(size_t)(bg + b)*Ff*OC + (size_t)(i + 1)*OC + o] = s_rb[o] + p;
    }
  }
}

extern "C" void kernel_launch(void* const* d_in, const int* in_sizes, int n_in,
                              void* d_out, int out_size, void* d_ws, size_t ws_size,
                              hipStream_t stream)
{
  (void)in_sizes; (void)n_in; (void)out_size; (void)ws_size;
  const float* y_past = (const float*)d_in[0];
  const float* t_in   = (const float*)d_in[1];
  const float* coeffs = (const float*)d_in[2];
  // d_in[3] = input_length (fixed 256)
  const float* zx_wih = (const float*)d_in[4];
  const float* zx_whh = (const float*)d_in[5];
  const float* zx_b   = (const float*)d_in[6];
  const float* zx_bn  = (const float*)d_in[7];
  const float* zxl_w  = (const float*)d_in[8];
  const float* zxl_b  = (const float*)d_in[9];
  const float* zy_wih = (const float*)d_in[10];
  const float* zy_whh = (const float*)d_in[11];
  const float* zy_b   = (const float*)d_in[12];
  const float* zy_bn  = (const float*)d_in[13];
  const float* fw1 = (const float*)d_in[14];
  const float* fb1 = (const float*)d_in[15];
  const float* fw2 = (const float*)d_in[16];
  const float* fb2 = (const float*)d_in[17];
  const float* fw3 = (const float*)d_in[18];
  const float* fb3 = (const float*)d_in[19];
  const float* r_w = (const float*)d_in[20];
  const float* r_b = (const float*)d_in[21];

  float* ws = (float*)d_ws;
  float* zx_buf = ws;                              // B*T*NZ fp32 = 8.39 MB
  float* zy_buf = ws + (size_t)Bb*Tt*NZ;           // B*H fp32   = 256 KB

  gru_kernel<<<Bb, 768, 0, stream>>>(coeffs, nullptr, t_in,
                                     zx_wih, zx_whh, zx_b, zx_bn,
                                     zxl_w, zxl_b, zx_buf, nullptr, Tt, 0);
  gru_kernel<<<Bb, 768, 0, stream>>>(y_past, zx_buf, t_in,
                                     zy_wih, zy_whh, zy_b, zy_bn,
                                     nullptr, nullptr, nullptr, zy_buf, Ll, 1);
  cde_fp32_kernel<<<Bb/BBt, 512, 0, stream>>>(zy_buf, zx_buf, t_in,
                                              fw1, fb1, fw2, fb2, fw3, fb3,
                                              r_w, r_b, (float*)d_out);
}

// Round 17
// 13538.889 us; speedup vs baseline: 1.9144x; 1.0003x over previous
//
#include <hip/hip_runtime.h>

#define Bb 512
#define Tt 512
#define Ll 256
#define Ff 256
#define Hh 128
#define H3 384
#define NZ 8
#define XC 16
#define OC 8
#define CF 9
#define W3N 1152
#define BBt 2     // batches per CDE block -> 256 blocks (1/CU)

__device__ __forceinline__ float sigm(float x){ return 1.0f/(1.0f+expf(-x)); }
__device__ __forceinline__ float softplus_(float x){
  return fmaxf(x, 0.0f) + log1pf(expf(-fabsf(x)));
}
__device__ __forceinline__ float tanh_fast(float x){   // phase-B only; |err|~1e-7
  float xc = fminf(fmaxf(x, -9.f), 9.f);
  float e = __expf(2.f*xc);
  return (e - 1.f)/(e + 1.f);
}
__device__ __forceinline__ float dot4(float4 w, float4 z){
  return w.x*z.x + w.y*z.y + w.z*z.z + w.w*z.w;
}
// involutive float4-index swizzle for [32]-float4 state rows
__device__ __forceinline__ int swz32(int i){ return i ^ ((i >> 3) & 3); }
__device__ __forceinline__ int swzf(int h){ return (((h >> 2) ^ ((h >> 5) & 3)) << 2) + (h & 3); }
// sum over lane bits 0..1 (q4 groups): pure-DPP butterfly (no DS) [HW-proven r15]
__device__ __forceinline__ float red4(float p){
  int t;
  t = __builtin_amdgcn_mov_dpp(__builtin_bit_cast(int, p), 0xB1, 0xF, 0xF, true); // xor1
  p += __builtin_bit_cast(float, t);
  t = __builtin_amdgcn_mov_dpp(__builtin_bit_cast(int, p), 0x4E, 0xF, 0xF, true); // xor2
  p += __builtin_bit_cast(float, t);
  return p;
}
// sum over lane bits 0..2 (e8 groups): 2 DPP + 1 ds_swizzle [HW-proven r15]
__device__ __forceinline__ float red8(float p){
  p = red4(p);
  int t = __builtin_amdgcn_ds_swizzle(__builtin_bit_cast(int, p), 0x101F);        // xor4
  p += __builtin_bit_cast(float, t);
  return p;
}

// ---------------- GRU v4: 768 threads; shfl projection, transposed zxlw -------
__global__ __launch_bounds__(768) void gru_kernel(
    const float* __restrict__ xin, const float* __restrict__ zx_in,
    const float* __restrict__ tin,
    const float* __restrict__ wih, const float* __restrict__ whh,
    const float* __restrict__ bias, const float* __restrict__ bn,
    const float* __restrict__ zxlw, const float* __restrict__ zxlb,
    float* __restrict__ out_zx, float* __restrict__ out_h,
    int steps, int mode)
{
  const int b = blockIdx.x;
  const int tid = threadIdx.x;
  const int j = tid >> 1;
  const int half = tid & 1;

  float wi[17];
  #pragma unroll
  for (int c = 0; c < 17; c++) wi[c] = wih[j*17 + c];
  const float bj = bias[j];
  float4 wr[16];
  {
    const float4* p = reinterpret_cast<const float4*>(whh + (size_t)j*Hh + half*64);
    #pragma unroll
    for (int q = 0; q < 16; q++) wr[q] = p[q];
  }

  __shared__ __align__(16) float s_h[Hh];
  __shared__ float s_i[H3];
  __shared__ float s_g[H3];
  __shared__ float s_x[17];
  __shared__ float s_bn[Hh];
  __shared__ float s_zxlwT[NZ*Hh];   // [q][o*16+m]  (conflict-free per-q reads)
  __shared__ float s_zxlb[NZ];

  if (tid < Hh){ s_h[tid] = 0.0f; s_bn[tid] = bn[tid]; }
  if (mode == 0){
    for (int q2 = tid; q2 < NZ*Hh; q2 += 768){
      int o = q2 >> 7, rem = q2 & 127, m = rem >> 3, q = rem & 7;
      s_zxlwT[q*128 + o*16 + m] = zxlw[q2];
    }
    if (tid < NZ) s_zxlb[tid] = zxlb[tid];
  }

  float xreg = 0.f;
  if (tid < 17){
    if (mode == 0){
      xreg = (tid < 16) ? xin[(size_t)b*Tt*XC + tid] : tin[0];
    } else {
      if (tid < 8)       xreg = xin[(size_t)b*Ll*NZ + tid];
      else if (tid < 16) xreg = zx_in[(size_t)b*Tt*NZ + (tid - 8)];
      else               xreg = tin[0];
    }
  }
  __syncthreads();

  for (int t = 0; t < steps; t++){
    if (tid < 17) s_x[tid] = xreg;
    __syncthreads();
    float ai = bj;
    #pragma unroll
    for (int c = 0; c < 17; c++) ai += wi[c]*s_x[c];
    float g0=0.f, g1=0.f, g2=0.f, g3=0.f;
    {
      const float4* h4p = reinterpret_cast<const float4*>(&s_h[half*64]);
      #pragma unroll
      for (int q = 0; q < 16; q++){
        float4 w = wr[q];
        float4 h4 = h4p[q];
        g0 += w.x*h4.x; g1 += w.y*h4.y; g2 += w.z*h4.z; g3 += w.w*h4.w;
      }
    }
    float g = (g0+g1)+(g2+g3);
    g += __shfl_xor(g, 1, 64);
    if (half == 0){ s_i[j] = ai; s_g[j] = g; }
    if (tid < 17 && t + 1 < steps){
      const int tn = t + 1;
      if (mode == 0){
        xreg = (tid < 16) ? xin[(size_t)b*Tt*XC + (size_t)tn*XC + tid] : tin[tn];
      } else {
        if (tid < 8)       xreg = xin[(size_t)b*Ll*NZ + (size_t)tn*NZ + tid];
        else if (tid < 16) xreg = zx_in[(size_t)b*Tt*NZ + (size_t)tn*NZ + (tid - 8)];
        else               xreg = tin[tn];
      }
    }
    __syncthreads();
    if (tid < Hh){
      float r  = sigm(s_i[tid]       + s_g[tid]);
      float zz = sigm(s_i[Hh + tid]  + s_g[Hh + tid]);
      float n  = tanhf(s_i[2*Hh+tid] + r*(s_g[2*Hh+tid] + s_bn[tid]));
      s_h[tid] = n + zz*(s_h[tid] - n);
    }
    __syncthreads();
    if (mode == 0){
      // projection via in-wave shfl reduce; conflict-free zxlwT reads; NO barriers
      // (s_h next written only after 2 barriers of step t+1 -> race-free)
      if (tid < Hh){
        int m = tid & 15;
        const float4* hp = reinterpret_cast<const float4*>(&s_h[m*8]);
        float4 ha = hp[0], hb = hp[1];
        float p = s_zxlwT[0*128 + tid]*ha.x + s_zxlwT[1*128 + tid]*ha.y
                + s_zxlwT[2*128 + tid]*ha.z + s_zxlwT[3*128 + tid]*ha.w
                + s_zxlwT[4*128 + tid]*hb.x + s_zxlwT[5*128 + tid]*hb.y
                + s_zxlwT[6*128 + tid]*hb.z + s_zxlwT[7*128 + tid]*hb.w;
        p += __shfl_xor(p, 1, 64); p += __shfl_xor(p, 2, 64);
        p += __shfl_xor(p, 4, 64); p += __shfl_xor(p, 8, 64);
        if (m == 0)
          out_zx[(size_t)b*Tt*NZ + (size_t)t*NZ + (tid >> 4)] = s_zxlb[tid >> 4] + p;
      }
    }
  }
  if (mode == 1 && tid < Hh) out_h[b*Hh + tid] = s_h[tid];
}

// ---------------- CDE RK4 v12 — r16 shape (92 VGPR) + split phase B -----------
// 256 blocks (1/CU) x 2 batches x 512 threads (the allocator-safe config).
__global__ __launch_bounds__(512)
__attribute__((amdgpu_waves_per_eu(2, 2)))
void cde_fp32_kernel(
    const float* __restrict__ zy_h, const float* __restrict__ zx,
    const float* __restrict__ tin,
    const float* __restrict__ fw1, const float* __restrict__ fb1,
    const float* __restrict__ fw2, const float* __restrict__ fb2,
    const float* __restrict__ fw3, const float* __restrict__ fb3,
    const float* __restrict__ rw,  const float* __restrict__ rb,
    float* __restrict__ yout)
{
  const int tid = threadIdx.x;
  const int c12 = tid >> 2;      // G1/G2: output col 0..127
  const int q4  = tid & 3;       // G1/G2: k-quarter
  const int col64 = tid >> 3;    // G3: col-in-group 0..63
  const int e8    = tid & 7;     // G3: k-eighth (16 floats)
  const int bg = blockIdx.x * BBt;

  __shared__ __align__(16) float4 s_w1v[4096];   // 64 KB, [jj][col*4+q4]
  __shared__ __align__(16) float4 s_w2v[4096];   // 64 KB
  __shared__ __align__(16) float4 s_zinv[BBt][32];  // swizzled state rows
  __shared__ __align__(16) float4 s_h1v[BBt][32];
  __shared__ __align__(16) float4 s_h2v[BBt][32];
  __shared__ float s_o[BBt][W3N];                // raw pre-activations
  __shared__ float s_z[BBt][Hh];
  __shared__ float s_kacc[BBt][Hh];
  __shared__ float s_dx[BBt][CF];
  __shared__ float s_rw[OC*Hh];
  __shared__ float s_rb[OC];
  __shared__ float s_b3[W3N];

  float* zin_f0 = reinterpret_cast<float*>(&s_zinv[0][0]);
  float* zin_f1 = reinterpret_cast<float*>(&s_zinv[1][0]);
  float* h1_f0  = reinterpret_cast<float*>(&s_h1v[0][0]);
  float* h1_f1  = reinterpret_cast<float*>(&s_h1v[1][0]);
  float* h2_f0  = reinterpret_cast<float*>(&s_h2v[0][0]);
  float* h2_f1  = reinterpret_cast<float*>(&s_h2v[1][0]);

  // ---- one-time: w1/w2 -> [jj][col*4+q] layout; biases, readout, init ----
  for (int idx = tid; idx < Hh*32; idx += 512){
    int col = idx >> 5, jcol = idx & 31;
    int q = jcol >> 3, jj = jcol & 7;
    int dst = jj*512 + col*4 + q;
    s_w1v[dst] = reinterpret_cast<const float4*>(fw1)[idx];
    s_w2v[dst] = reinterpret_cast<const float4*>(fw2)[idx];
  }
  const float b1r = fb1[c12], b2r = fb2[c12];
  for (int idx = tid; idx < W3N; idx += 512) s_b3[idx] = fb3[idx];
  for (int idx = tid; idx < OC*Hh; idx += 512) s_rw[idx] = rw[idx];
  if (tid < OC) s_rb[tid] = rb[tid];
  if (tid < BBt*Hh){
    int b = tid >> 7, h = tid & 127;
    float zv = zy_h[(size_t)(bg + b)*Hh + h];
    s_z[b][h] = zv;
    (b == 0 ? zin_f0 : zin_f1)[swzf(h)] = zv;
  }
  __syncthreads();

  // y[:, 0, :]
  if (tid < 256){
    int b = tid >> 7, r = tid & 127, o = r >> 4, seg = r & 15;
    float p = 0.f;
    #pragma unroll
    for (int q = 0; q < 8; q++)
      p += s_z[b][seg*8 + q]*s_rw[o*Hh + seg*8 + q];
    p += __shfl_xor(p, 1, 64); p += __shfl_xor(p, 2, 64);
    p += __shfl_xor(p, 4, 64); p += __shfl_xor(p, 8, 64);
    if (seg == 0) yout[(size_t)(bg + b)*Ff*OC + o] = s_rb[o] + p;
  }

  const float* w3p = fw3 + (size_t)col64*Hh + e8*16;   // + g*8192 floats per iter

  for (int i = 0; i < Ff - 1; i++){
    if (tid < BBt*CF){
      int b = tid/CF, c = tid%CF;
      float d;
      if (c < 8){
        const float* zp = zx + (size_t)(bg + b)*Tt*NZ + (size_t)(Ll + i)*NZ + c;
        d = zp[NZ] - zp[0];
      } else {
        d = tin[Ll + i + 1] - tin[Ll + i];
      }
      s_dx[b][c] = d;
    }
    __syncthreads();

    for (int st = 0; st < 4; st++){
      // ---- issue w3 iters 0,1 now; latency hides under G1/G2 (2-deep only!) ----
      float4 A0, A1, A2, A3, B0, B1, B2, B3;
      {
        const float4* pA = reinterpret_cast<const float4*>(w3p);
        const float4* pB = reinterpret_cast<const float4*>(w3p + 8192);
        A0 = pA[0]; A1 = pA[1]; A2 = pA[2]; A3 = pA[3];
        B0 = pB[0]; B1 = pB[1]; B2 = pB[2]; B3 = pB[3];
      }
      // ---- G1: h1 = softplus(zin @ w1.T + b1); DPP reduce (no DS) ----
      {
        float p0 = 0.f, p1 = 0.f;
        #pragma unroll
        for (int jj = 0; jj < 8; jj++){
          float4 z0 = s_zinv[0][swz32(q4*8 + jj)];
          float4 z1 = s_zinv[1][swz32(q4*8 + jj)];
          float4 w = s_w1v[jj*512 + tid];
          p0 += dot4(w, z0); p1 += dot4(w, z1);
        }
        p0 = red4(p0); p1 = red4(p1);
        if (q4 == 0){
          h1_f0[swzf(c12)] = softplus_(b1r + p0);
          h1_f1[swzf(c12)] = softplus_(b1r + p1);
        }
      }
      __syncthreads();
      // ---- G2 ----
      {
        float p0 = 0.f, p1 = 0.f;
        #pragma unroll
        for (int jj = 0; jj < 8; jj++){
          float4 z0 = s_h1v[0][swz32(q4*8 + jj)];
          float4 z1 = s_h1v[1][swz32(q4*8 + jj)];
          float4 w = s_w2v[jj*512 + tid];
          p0 += dot4(w, z0); p1 += dot4(w, z1);
        }
        p0 = red4(p0); p1 = red4(p1);
        if (q4 == 0){
          h2_f0[swzf(c12)] = softplus_(b2r + p0);
          h2_f1[swzf(c12)] = softplus_(b2r + p1);
        }
      }
      __syncthreads();
      // ---- G3: 18 iters, 2-deep A/B pipeline, red8 (2 DPP + 1 DS) ----
      {
        float4 h2a0 = s_h2v[0][swz32(e8*4 + 0)];
        float4 h2a1 = s_h2v[0][swz32(e8*4 + 1)];
        float4 h2a2 = s_h2v[0][swz32(e8*4 + 2)];
        float4 h2a3 = s_h2v[0][swz32(e8*4 + 3)];
        float4 h2b0 = s_h2v[1][swz32(e8*4 + 0)];
        float4 h2b1 = s_h2v[1][swz32(e8*4 + 1)];
        float4 h2b2 = s_h2v[1][swz32(e8*4 + 2)];
        float4 h2b3 = s_h2v[1][swz32(e8*4 + 3)];
        #pragma unroll 2
        for (int g = 0; g < 18; g++){
          float4 c0, c1, c2, c3;
          if ((g & 1) == 0){
            c0 = A0; c1 = A1; c2 = A2; c3 = A3;
            if (g + 2 < 18){
              const float4* pF = reinterpret_cast<const float4*>(w3p + (size_t)(g+2)*8192);
              A0 = pF[0]; A1 = pF[1]; A2 = pF[2]; A3 = pF[3];
            }
          } else {
            c0 = B0; c1 = B1; c2 = B2; c3 = B3;
            if (g + 2 < 18){
              const float4* pF = reinterpret_cast<const float4*>(w3p + (size_t)(g+2)*8192);
              B0 = pF[0]; B1 = pF[1]; B2 = pF[2]; B3 = pF[3];
            }
          }
          float p0 = dot4(c0, h2a0) + dot4(c1, h2a1) + dot4(c2, h2a2) + dot4(c3, h2a3);
          float p1 = dot4(c0, h2b0) + dot4(c1, h2b1) + dot4(c2, h2b2) + dot4(c3, h2b3);
          p0 = red8(p0); p1 = red8(p1);
          if (e8 == 0){
            int n = g*64 + col64;
            s_o[0][n] = s_b3[n] + p0;
            s_o[1][n] = s_b3[n] + p1;
          }
        }
      }
      __syncthreads();
      // ---- phase B: 512 threads = 256 pairs x 2 halves; shfl(1) combine ----
      {
        int pr = tid >> 1, hf = tid & 1;
        int b = pr >> 7, h = pr & 127;
        const float* ob = &s_o[0][0] + b*W3N + h*CF;
        float kc = 0.f;
        #pragma unroll
        for (int jj = 0; jj < 4; jj++){
          int c = hf*4 + jj;
          kc += tanh_fast(ob[c]) * s_dx[b][c];
        }
        if (hf) kc += tanh_fast(ob[8]) * s_dx[b][8];
        kc += __shfl_xor(kc, 1, 64);
        if (hf == 0){
          float zv = s_z[b][h], zin;
          if      (st == 0){ s_kacc[b][h] = kc;        zin = zv + 0.5f*kc; }
          else if (st == 1){ s_kacc[b][h] += 2.f*kc;   zin = zv + 0.5f*kc; }
          else if (st == 2){ s_kacc[b][h] += 2.f*kc;   zin = zv + kc; }
          else { float zn = zv + (s_kacc[b][h] + kc)*(1.f/6.f); s_z[b][h] = zn; zin = zn; }
          (b == 0 ? zin_f0 : zin_f1)[swzf(h)] = zin;
        }
      }
      __syncthreads();
    }
    // readout y[:, i+1, :]
    if (tid < 256){
      int b = tid >> 7, r = tid & 127, o = r >> 4, seg = r & 15;
      float p = 0.f;
      #pragma unroll
      for (int q = 0; q < 8; q++)
        p += s_z[b][seg*8 + q]*s_rw[o*Hh + seg*8 + q];
      p += __shfl_xor(p, 1, 64); p += __shfl_xor(p, 2, 64);
      p += __shfl_xor(p, 4, 64); p += __shfl_xor(p, 8, 64);
      if (seg == 0) yout[(size_t)(bg + b)*Ff*OC + (size_t)(i + 1)*OC + o] = s_rb[o] + p;
    }
  }
}

extern "C" void kernel_launch(void* const* d_in, const int* in_sizes, int n_in,
                              void* d_out, int out_size, void* d_ws, size_t ws_size,
                              hipStream_t stream)
{
  (void)in_sizes; (void)n_in; (void)out_size; (void)ws_size;
  const float* y_past = (const float*)d_in[0];
  const float* t_in   = (const float*)d_in[1];
  const float* coeffs = (const float*)d_in[2];
  // d_in[3] = input_length (fixed 256)
  const float* zx_wih = (const float*)d_in[4];
  const float* zx_whh = (const float*)d_in[5];
  const float* zx_b   = (const float*)d_in[6];
  const float* zx_bn  = (const float*)d_in[7];
  const float* zxl_w  = (const float*)d_in[8];
  const float* zxl_b  = (const float*)d_in[9];
  const float* zy_wih = (const float*)d_in[10];
  const float* zy_whh = (const float*)d_in[11];
  const float* zy_b   = (const float*)d_in[12];
  const float* zy_bn  = (const float*)d_in[13];
  const float* fw1 = (const float*)d_in[14];
  const float* fb1 = (const float*)d_in[15];
  const float* fw2 = (const float*)d_in[16];
  const float* fb2 = (const float*)d_in[17];
  const float* fw3 = (const float*)d_in[18];
  const float* fb3 = (const float*)d_in[19];
  const float* r_w = (const float*)d_in[20];
  const float* r_b = (const float*)d_in[21];

  float* ws = (float*)d_ws;
  float* zx_buf = ws;                              // B*T*NZ fp32 = 8.39 MB
  float* zy_buf = ws + (size_t)Bb*Tt*NZ;           // B*H fp32   = 256 KB

  gru_kernel<<<Bb, 768, 0, stream>>>(coeffs, nullptr, t_in,
                                     zx_wih, zx_whh, zx_b, zx_bn,
                                     zxl_w, zxl_b, zx_buf, nullptr, Tt, 0);
  gru_kernel<<<Bb, 768, 0, stream>>>(y_past, zx_buf, t_in,
                                     zy_wih, zy_whh, zy_b, zy_bn,
                                     nullptr, nullptr, nullptr, zy_buf, Ll, 1);
  cde_fp32_kernel<<<Bb/BBt, 512, 0, stream>>>(zy_buf, zx_buf, t_in,
                                              fw1, fb1, fw2, fb2, fw3, fb3,
                                              r_w, r_b, (float*)d_out);
}

// Round 18
// 12001.025 us; speedup vs baseline: 2.1598x; 1.1281x over previous
//
#include <hip/hip_runtime.h>

#define Bb 512
#define Tt 512
#define Ll 256
#define Ff 256
#define Hh 128
#define H3 384
#define NZ 8
#define XC 16
#define OC 8
#define CF 9
#define W3N 1152
#define BBt 2     // batches per CDE block -> 256 blocks (1/CU)

__device__ __forceinline__ float sigm_fast(float x){ return 1.0f/(1.0f + __expf(-x)); }
__device__ __forceinline__ float softplus_fast(float x){
  float u = __expf(-fabsf(x));
  return fmaxf(x, 0.0f) + __logf(1.0f + u);
}
__device__ __forceinline__ float tanh_fast(float x){   // |err|~1e-7
  float xc = fminf(fmaxf(x, -9.f), 9.f);
  float e = __expf(2.f*xc);
  return (e - 1.f)/(e + 1.f);
}
__device__ __forceinline__ float dot4(float4 w, float4 z){
  return w.x*z.x + w.y*z.y + w.z*z.z + w.w*z.w;
}
// involutive float4-index swizzle for [32]-float4 state rows
__device__ __forceinline__ int swz32(int i){ return i ^ ((i >> 3) & 3); }
__device__ __forceinline__ int swzf(int h){ return (((h >> 2) ^ ((h >> 5) & 3)) << 2) + (h & 3); }
// sum over lane bits 0..1: pure-DPP butterfly (no DS) [HW-proven r15]
__device__ __forceinline__ float red4(float p){
  int t;
  t = __builtin_amdgcn_mov_dpp(__builtin_bit_cast(int, p), 0xB1, 0xF, 0xF, true); // xor1
  p += __builtin_bit_cast(float, t);
  t = __builtin_amdgcn_mov_dpp(__builtin_bit_cast(int, p), 0x4E, 0xF, 0xF, true); // xor2
  p += __builtin_bit_cast(float, t);
  return p;
}
// sum over lane bits 0..2: 2 DPP + 1 ds_swizzle [HW-proven r15]
__device__ __forceinline__ float red8(float p){
  p = red4(p);
  int t = __builtin_amdgcn_ds_swizzle(__builtin_bit_cast(int, p), 0x101F);        // xor4
  p += __builtin_bit_cast(float, t);
  return p;
}

// ---------------- GRU v5: fused zx(512 steps) + zy(256 steps) per block -------
// 768 threads, 2 threads/gate-row. zx history t<256 passes through LDS (8KB);
// zx global writes only t>=256 (all cde reads). No inter-dispatch global sync.
__global__ __launch_bounds__(768) void gru_fused_kernel(
    const float* __restrict__ coeffs, const float* __restrict__ y_past,
    const float* __restrict__ tin,
    const float* __restrict__ zx_wih, const float* __restrict__ zx_whh,
    const float* __restrict__ zx_b,   const float* __restrict__ zx_bn,
    const float* __restrict__ zxlw,   const float* __restrict__ zxlb,
    const float* __restrict__ zy_wih, const float* __restrict__ zy_whh,
    const float* __restrict__ zy_b,   const float* __restrict__ zy_bn,
    float* __restrict__ out_zx, float* __restrict__ out_h)
{
  const int b = blockIdx.x;
  const int tid = threadIdx.x;
  const int j = tid >> 1;
  const int half = tid & 1;

  __shared__ __align__(16) float s_h[Hh];
  __shared__ float s_i[H3];
  __shared__ float s_g[H3];
  __shared__ float s_x[17];
  __shared__ float s_bn[Hh];
  __shared__ float s_zxlwT[NZ*Hh];   // [q][o*16+m]  (conflict-free per-q reads)
  __shared__ float s_zxlb[NZ];
  __shared__ float s_zxh[Ll][NZ];    // zx history for the zy phase (8KB)

  // ================= PHASE A: zx encoder, 512 steps =================
  {
    float wi[17];
    #pragma unroll
    for (int c = 0; c < 17; c++) wi[c] = zx_wih[j*17 + c];
    const float bj = zx_b[j];
    float4 wr[16];
    {
      const float4* p = reinterpret_cast<const float4*>(zx_whh + (size_t)j*Hh + half*64);
      #pragma unroll
      for (int q = 0; q < 16; q++) wr[q] = p[q];
    }

    if (tid < Hh){ s_h[tid] = 0.0f; s_bn[tid] = zx_bn[tid]; }
    for (int q2 = tid; q2 < NZ*Hh; q2 += 768){
      int o = q2 >> 7, rem = q2 & 127, m = rem >> 3, q = rem & 7;
      s_zxlwT[q*128 + o*16 + m] = zxlw[q2];
    }
    if (tid < NZ) s_zxlb[tid] = zxlb[tid];

    float xreg = 0.f;
    if (tid < 17)
      xreg = (tid < 16) ? coeffs[(size_t)b*Tt*XC + tid] : tin[0];
    __syncthreads();

    for (int t = 0; t < Tt; t++){
      if (tid < 17) s_x[tid] = xreg;
      __syncthreads();
      float ai = bj;
      #pragma unroll
      for (int c = 0; c < 17; c++) ai += wi[c]*s_x[c];
      float g0=0.f, g1=0.f, g2=0.f, g3=0.f;
      {
        const float4* h4p = reinterpret_cast<const float4*>(&s_h[half*64]);
        #pragma unroll
        for (int q = 0; q < 16; q++){
          float4 w = wr[q];
          float4 h4 = h4p[q];
          g0 += w.x*h4.x; g1 += w.y*h4.y; g2 += w.z*h4.z; g3 += w.w*h4.w;
        }
      }
      float g = (g0+g1)+(g2+g3);
      g += __shfl_xor(g, 1, 64);
      if (half == 0){ s_i[j] = ai; s_g[j] = g; }
      if (tid < 17 && t + 1 < Tt){
        const int tn = t + 1;
        xreg = (tid < 16) ? coeffs[(size_t)b*Tt*XC + (size_t)tn*XC + tid] : tin[tn];
      }
      __syncthreads();
      if (tid < Hh){
        float r  = sigm_fast(s_i[tid]       + s_g[tid]);
        float zz = sigm_fast(s_i[Hh + tid]  + s_g[Hh + tid]);
        float n  = tanh_fast(s_i[2*Hh+tid] + r*(s_g[2*Hh+tid] + s_bn[tid]));
        s_h[tid] = n + zz*(s_h[tid] - n);
      }
      __syncthreads();
      // projection (no barrier; s_h next written 2 barriers into step t+1)
      if (tid < Hh){
        int m = tid & 15;
        const float4* hp = reinterpret_cast<const float4*>(&s_h[m*8]);
        float4 ha = hp[0], hb = hp[1];
        float p = s_zxlwT[0*128 + tid]*ha.x + s_zxlwT[1*128 + tid]*ha.y
                + s_zxlwT[2*128 + tid]*ha.z + s_zxlwT[3*128 + tid]*ha.w
                + s_zxlwT[4*128 + tid]*hb.x + s_zxlwT[5*128 + tid]*hb.y
                + s_zxlwT[6*128 + tid]*hb.z + s_zxlwT[7*128 + tid]*hb.w;
        p += __shfl_xor(p, 1, 64); p += __shfl_xor(p, 2, 64);
        p += __shfl_xor(p, 4, 64); p += __shfl_xor(p, 8, 64);
        if (m == 0){
          int o = tid >> 4;
          float val = s_zxlb[o] + p;
          if (t < Ll) s_zxh[t][o] = val;                      // zy phase consumes
          else out_zx[(size_t)b*Tt*NZ + (size_t)t*NZ + o] = val;  // cde consumes
        }
      }
    }
  }
  __syncthreads();   // phase-A projection done before state reset

  // ================= PHASE B: zy encoder, 256 steps =================
  {
    float wi[17];
    #pragma unroll
    for (int c = 0; c < 17; c++) wi[c] = zy_wih[j*17 + c];
    const float bj = zy_b[j];
    float4 wr[16];
    {
      const float4* p = reinterpret_cast<const float4*>(zy_whh + (size_t)j*Hh + half*64);
      #pragma unroll
      for (int q = 0; q < 16; q++) wr[q] = p[q];
    }
    if (tid < Hh){ s_h[tid] = 0.0f; s_bn[tid] = zy_bn[tid]; }

    float xreg = 0.f;
    if (tid < 8)        xreg = y_past[(size_t)b*Ll*NZ + tid];
    else if (tid == 16) xreg = tin[0];
    __syncthreads();

    for (int t = 0; t < Ll; t++){
      if (tid < 8)        s_x[tid] = xreg;
      else if (tid < 16)  s_x[tid] = s_zxh[t][tid - 8];
      else if (tid == 16) s_x[16] = xreg;
      __syncthreads();
      float ai = bj;
      #pragma unroll
      for (int c = 0; c < 17; c++) ai += wi[c]*s_x[c];
      float g0=0.f, g1=0.f, g2=0.f, g3=0.f;
      {
        const float4* h4p = reinterpret_cast<const float4*>(&s_h[half*64]);
        #pragma unroll
        for (int q = 0; q < 16; q++){
          float4 w = wr[q];
          float4 h4 = h4p[q];
          g0 += w.x*h4.x; g1 += w.y*h4.y; g2 += w.z*h4.z; g3 += w.w*h4.w;
        }
      }
      float g = (g0+g1)+(g2+g3);
      g += __shfl_xor(g, 1, 64);
      if (half == 0){ s_i[j] = ai; s_g[j] = g; }
      if (t + 1 < Ll){
        if (tid < 8)        xreg = y_past[(size_t)b*Ll*NZ + (size_t)(t+1)*NZ + tid];
        else if (tid == 16) xreg = tin[t+1];
      }
      __syncthreads();
      if (tid < Hh){
        float r  = sigm_fast(s_i[tid]       + s_g[tid]);
        float zz = sigm_fast(s_i[Hh + tid]  + s_g[Hh + tid]);
        float n  = tanh_fast(s_i[2*Hh+tid] + r*(s_g[2*Hh+tid] + s_bn[tid]));
        s_h[tid] = n + zz*(s_h[tid] - n);
      }
      __syncthreads();
    }
    if (tid < Hh) out_h[b*Hh + tid] = s_h[tid];
  }
}

// ---------------- CDE RK4 v13 — r17 shape (92 VGPR) + softplus_fast -----------
// 256 blocks (1/CU) x 2 batches x 512 threads (the allocator-safe config).
__global__ __launch_bounds__(512)
__attribute__((amdgpu_waves_per_eu(2, 2)))
void cde_fp32_kernel(
    const float* __restrict__ zy_h, const float* __restrict__ zx,
    const float* __restrict__ tin,
    const float* __restrict__ fw1, const float* __restrict__ fb1,
    const float* __restrict__ fw2, const float* __restrict__ fb2,
    const float* __restrict__ fw3, const float* __restrict__ fb3,
    const float* __restrict__ rw,  const float* __restrict__ rb,
    float* __restrict__ yout)
{
  const int tid = threadIdx.x;
  const int c12 = tid >> 2;      // G1/G2: output col 0..127
  const int q4  = tid & 3;       // G1/G2: k-quarter
  const int col64 = tid >> 3;    // G3: col-in-group 0..63
  const int e8    = tid & 7;     // G3: k-eighth (16 floats)
  const int bg = blockIdx.x * BBt;

  __shared__ __align__(16) float4 s_w1v[4096];   // 64 KB, [jj][col*4+q4]
  __shared__ __align__(16) float4 s_w2v[4096];   // 64 KB
  __shared__ __align__(16) float4 s_zinv[BBt][32];  // swizzled state rows
  __shared__ __align__(16) float4 s_h1v[BBt][32];
  __shared__ __align__(16) float4 s_h2v[BBt][32];
  __shared__ float s_o[BBt][W3N];                // raw pre-activations
  __shared__ float s_z[BBt][Hh];
  __shared__ float s_kacc[BBt][Hh];
  __shared__ float s_dx[BBt][CF];
  __shared__ float s_rw[OC*Hh];
  __shared__ float s_rb[OC];
  __shared__ float s_b3[W3N];

  float* zin_f0 = reinterpret_cast<float*>(&s_zinv[0][0]);
  float* zin_f1 = reinterpret_cast<float*>(&s_zinv[1][0]);
  float* h1_f0  = reinterpret_cast<float*>(&s_h1v[0][0]);
  float* h1_f1  = reinterpret_cast<float*>(&s_h1v[1][0]);
  float* h2_f0  = reinterpret_cast<float*>(&s_h2v[0][0]);
  float* h2_f1  = reinterpret_cast<float*>(&s_h2v[1][0]);

  // ---- one-time: w1/w2 -> [jj][col*4+q] layout; biases, readout, init ----
  for (int idx = tid; idx < Hh*32; idx += 512){
    int col = idx >> 5, jcol = idx & 31;
    int q = jcol >> 3, jj = jcol & 7;
    int dst = jj*512 + col*4 + q;
    s_w1v[dst] = reinterpret_cast<const float4*>(fw1)[idx];
    s_w2v[dst] = reinterpret_cast<const float4*>(fw2)[idx];
  }
  const float b1r = fb1[c12], b2r = fb2[c12];
  for (int idx = tid; idx < W3N; idx += 512) s_b3[idx] = fb3[idx];
  for (int idx = tid; idx < OC*Hh; idx += 512) s_rw[idx] = rw[idx];
  if (tid < OC) s_rb[tid] = rb[tid];
  if (tid < BBt*Hh){
    int b = tid >> 7, h = tid & 127;
    float zv = zy_h[(size_t)(bg + b)*Hh + h];
    s_z[b][h] = zv;
    (b == 0 ? zin_f0 : zin_f1)[swzf(h)] = zv;
  }
  __syncthreads();

  // y[:, 0, :]
  if (tid < 256){
    int b = tid >> 7, r = tid & 127, o = r >> 4, seg = r & 15;
    float p = 0.f;
    #pragma unroll
    for (int q = 0; q < 8; q++)
      p += s_z[b][seg*8 + q]*s_rw[o*Hh + seg*8 + q];
    p += __shfl_xor(p, 1, 64); p += __shfl_xor(p, 2, 64);
    p += __shfl_xor(p, 4, 64); p += __shfl_xor(p, 8, 64);
    if (seg == 0) yout[(size_t)(bg + b)*Ff*OC + o] = s_rb[o] + p;
  }

  const float* w3p = fw3 + (size_t)col64*Hh + e8*16;   // + g*8192 floats per iter

  for (int i = 0; i < Ff - 1; i++){
    if (tid < BBt*CF){
      int b = tid/CF, c = tid%CF;
      float d;
      if (c < 8){
        const float* zp = zx + (size_t)(bg + b)*Tt*NZ + (size_t)(Ll + i)*NZ + c;
        d = zp[NZ] - zp[0];
      } else {
        d = tin[Ll + i + 1] - tin[Ll + i];
      }
      s_dx[b][c] = d;
    }
    __syncthreads();

    for (int st = 0; st < 4; st++){
      // ---- issue w3 iters 0,1 now; latency hides under G1/G2 (2-deep only!) ----
      float4 A0, A1, A2, A3, B0, B1, B2, B3;
      {
        const float4* pA = reinterpret_cast<const float4*>(w3p);
        const float4* pB = reinterpret_cast<const float4*>(w3p + 8192);
        A0 = pA[0]; A1 = pA[1]; A2 = pA[2]; A3 = pA[3];
        B0 = pB[0]; B1 = pB[1]; B2 = pB[2]; B3 = pB[3];
      }
      // ---- G1: h1 = softplus(zin @ w1.T + b1); DPP reduce (no DS) ----
      {
        float p0 = 0.f, p1 = 0.f;
        #pragma unroll
        for (int jj = 0; jj < 8; jj++){
          float4 z0 = s_zinv[0][swz32(q4*8 + jj)];
          float4 z1 = s_zinv[1][swz32(q4*8 + jj)];
          float4 w = s_w1v[jj*512 + tid];
          p0 += dot4(w, z0); p1 += dot4(w, z1);
        }
        p0 = red4(p0); p1 = red4(p1);
        if (q4 == 0){
          h1_f0[swzf(c12)] = softplus_fast(b1r + p0);
          h1_f1[swzf(c12)] = softplus_fast(b1r + p1);
        }
      }
      __syncthreads();
      // ---- G2 ----
      {
        float p0 = 0.f, p1 = 0.f;
        #pragma unroll
        for (int jj = 0; jj < 8; jj++){
          float4 z0 = s_h1v[0][swz32(q4*8 + jj)];
          float4 z1 = s_h1v[1][swz32(q4*8 + jj)];
          float4 w = s_w2v[jj*512 + tid];
          p0 += dot4(w, z0); p1 += dot4(w, z1);
        }
        p0 = red4(p0); p1 = red4(p1);
        if (q4 == 0){
          h2_f0[swzf(c12)] = softplus_fast(b2r + p0);
          h2_f1[swzf(c12)] = softplus_fast(b2r + p1);
        }
      }
      __syncthreads();
      // ---- G3: 18 iters, 2-deep A/B pipeline, red8 (2 DPP + 1 DS) ----
      {
        float4 h2a0 = s_h2v[0][swz32(e8*4 + 0)];
        float4 h2a1 = s_h2v[0][swz32(e8*4 + 1)];
        float4 h2a2 = s_h2v[0][swz32(e8*4 + 2)];
        float4 h2a3 = s_h2v[0][swz32(e8*4 + 3)];
        float4 h2b0 = s_h2v[1][swz32(e8*4 + 0)];
        float4 h2b1 = s_h2v[1][swz32(e8*4 + 1)];
        float4 h2b2 = s_h2v[1][swz32(e8*4 + 2)];
        float4 h2b3 = s_h2v[1][swz32(e8*4 + 3)];
        #pragma unroll 2
        for (int g = 0; g < 18; g++){
          float4 c0, c1, c2, c3;
          if ((g & 1) == 0){
            c0 = A0; c1 = A1; c2 = A2; c3 = A3;
            if (g + 2 < 18){
              const float4* pF = reinterpret_cast<const float4*>(w3p + (size_t)(g+2)*8192);
              A0 = pF[0]; A1 = pF[1]; A2 = pF[2]; A3 = pF[3];
            }
          } else {
            c0 = B0; c1 = B1; c2 = B2; c3 = B3;
            if (g + 2 < 18){
              const float4* pF = reinterpret_cast<const float4*>(w3p + (size_t)(g+2)*8192);
              B0 = pF[0]; B1 = pF[1]; B2 = pF[2]; B3 = pF[3];
            }
          }
          float p0 = dot4(c0, h2a0) + dot4(c1, h2a1) + dot4(c2, h2a2) + dot4(c3, h2a3);
          float p1 = dot4(c0, h2b0) + dot4(c1, h2b1) + dot4(c2, h2b2) + dot4(c3, h2b3);
          p0 = red8(p0); p1 = red8(p1);
          if (e8 == 0){
            int n = g*64 + col64;
            s_o[0][n] = s_b3[n] + p0;
            s_o[1][n] = s_b3[n] + p1;
          }
        }
      }
      __syncthreads();
      // ---- phase B: 512 threads = 256 pairs x 2 halves; shfl(1) combine ----
      {
        int pr = tid >> 1, hf = tid & 1;
        int b = pr >> 7, h = pr & 127;
        const float* ob = &s_o[0][0] + b*W3N + h*CF;
        float kc = 0.f;
        #pragma unroll
        for (int jj = 0; jj < 4; jj++){
          int c = hf*4 + jj;
          kc += tanh_fast(ob[c]) * s_dx[b][c];
        }
        if (hf) kc += tanh_fast(ob[8]) * s_dx[b][8];
        kc += __shfl_xor(kc, 1, 64);
        if (hf == 0){
          float zv = s_z[b][h], zin;
          if      (st == 0){ s_kacc[b][h] = kc;        zin = zv + 0.5f*kc; }
          else if (st == 1){ s_kacc[b][h] += 2.f*kc;   zin = zv + 0.5f*kc; }
          else if (st == 2){ s_kacc[b][h] += 2.f*kc;   zin = zv + kc; }
          else { float zn = zv + (s_kacc[b][h] + kc)*(1.f/6.f); s_z[b][h] = zn; zin = zn; }
          (b == 0 ? zin_f0 : zin_f1)[swzf(h)] = zin;
        }
      }
      __syncthreads();
    }
    // readout y[:, i+1, :]
    if (tid < 256){
      int b = tid >> 7, r = tid & 127, o = r >> 4, seg = r & 15;
      float p = 0.f;
      #pragma unroll
      for (int q = 0; q < 8; q++)
        p += s_z[b][seg*8 + q]*s_rw[o*Hh + seg*8 + q];
      p += __shfl_xor(p, 1, 64); p += __shfl_xor(p, 2, 64);
      p += __shfl_xor(p, 4, 64); p += __shfl_xor(p, 8, 64);
      if (seg == 0) yout[(size_t)(bg + b)*Ff*OC + (size_t)(i + 1)*OC + o] = s_rb[o] + p;
    }
  }
}

extern "C" void kernel_launch(void* const* d_in, const int* in_sizes, int n_in,
                              void* d_out, int out_size, void* d_ws, size_t ws_size,
                              hipStream_t stream)
{
  (void)in_sizes; (void)n_in; (void)out_size; (void)ws_size;
  const float* y_past = (const float*)d_in[0];
  const float* t_in   = (const float*)d_in[1];
  const float* coeffs = (const float*)d_in[2];
  // d_in[3] = input_length (fixed 256)
  const float* zx_wih = (const float*)d_in[4];
  const float* zx_whh = (const float*)d_in[5];
  const float* zx_b   = (const float*)d_in[6];
  const float* zx_bn  = (const float*)d_in[7];
  const float* zxl_w  = (const float*)d_in[8];
  const float* zxl_b  = (const float*)d_in[9];
  const float* zy_wih = (const float*)d_in[10];
  const float* zy_whh = (const float*)d_in[11];
  const float* zy_b   = (const float*)d_in[12];
  const float* zy_bn  = (const float*)d_in[13];
  const float* fw1 = (const float*)d_in[14];
  const float* fb1 = (const float*)d_in[15];
  const float* fw2 = (const float*)d_in[16];
  const float* fb2 = (const float*)d_in[17];
  const float* fw3 = (const float*)d_in[18];
  const float* fb3 = (const float*)d_in[19];
  const float* r_w = (const float*)d_in[20];
  const float* r_b = (const float*)d_in[21];

  float* ws = (float*)d_ws;
  float* zx_buf = ws;                              // B*T*NZ fp32 = 8.39 MB
  float* zy_buf = ws + (size_t)Bb*Tt*NZ;           // B*H fp32   = 256 KB

  gru_fused_kernel<<<Bb, 768, 0, stream>>>(coeffs, y_past, t_in,
                                           zx_wih, zx_whh, zx_b, zx_bn,
                                           zxl_w, zxl_b,
                                           zy_wih, zy_whh, zy_b, zy_bn,
                                           zx_buf, zy_buf);
  cde_fp32_kernel<<<Bb/BBt, 512, 0, stream>>>(zy_buf, zx_buf, t_in,
                                              fw1, fb1, fw2, fb2, fw3, fb3,
                                              r_w, r_b, (float*)d_out);
}

// Round 19
// 11860.680 us; speedup vs baseline: 2.1853x; 1.0118x over previous
//
#include <hip/hip_runtime.h>

#define Bb 512
#define Tt 512
#define Ll 256
#define Ff 256
#define Hh 128
#define H3 384
#define NZ 8
#define XC 16
#define OC 8
#define CF 9
#define W3N 1152
#define BBt 2     // batches per CDE block -> 256 blocks (1/CU)

typedef float v2f __attribute__((ext_vector_type(2)));

__device__ __forceinline__ float sigm_fast(float x){ return 1.0f/(1.0f + __expf(-x)); }
__device__ __forceinline__ float softplus_fast(float x){
  float u = __expf(-fabsf(x));
  return fmaxf(x, 0.0f) + __logf(1.0f + u);
}
__device__ __forceinline__ float tanh_fast(float x){   // |err|~1e-7
  float xc = fminf(fmaxf(x, -9.f), 9.f);
  float e = __expf(2.f*xc);
  return (e - 1.f)/(e + 1.f);
}
// packed dual-FMA accumulate: acc += {w.x*z.x, w.y*z.y} twice per float4
__device__ __forceinline__ v2f pk4(float4 w, float4 z, v2f acc){
  v2f wl = {w.x, w.y}, wh = {w.z, w.w};
  v2f zl = {z.x, z.y}, zh = {z.z, z.w};
  acc += wl*zl;       // -> v_pk_fma_f32
  acc += wh*zh;
  return acc;
}
// involutive float4-index swizzle for [32]-float4 state rows
__device__ __forceinline__ int swz32(int i){ return i ^ ((i >> 3) & 3); }
__device__ __forceinline__ int swzf(int h){ return (((h >> 2) ^ ((h >> 5) & 3)) << 2) + (h & 3); }
// sum over lane bits 0..1: pure-DPP butterfly (no DS) [HW-proven r15]
__device__ __forceinline__ float red4(float p){
  int t;
  t = __builtin_amdgcn_mov_dpp(__builtin_bit_cast(int, p), 0xB1, 0xF, 0xF, true); // xor1
  p += __builtin_bit_cast(float, t);
  t = __builtin_amdgcn_mov_dpp(__builtin_bit_cast(int, p), 0x4E, 0xF, 0xF, true); // xor2
  p += __builtin_bit_cast(float, t);
  return p;
}
// sum over lane bits 0..2: 2 DPP + 1 ds_swizzle [HW-proven r15]
__device__ __forceinline__ float red8(float p){
  p = red4(p);
  int t = __builtin_amdgcn_ds_swizzle(__builtin_bit_cast(int, p), 0x101F);        // xor4
  p += __builtin_bit_cast(float, t);
  return p;
}

// ---------------- GRU v5: fused zx(512) + zy(256) per block (r18, unchanged) --
__global__ __launch_bounds__(768) void gru_fused_kernel(
    const float* __restrict__ coeffs, const float* __restrict__ y_past,
    const float* __restrict__ tin,
    const float* __restrict__ zx_wih, const float* __restrict__ zx_whh,
    const float* __restrict__ zx_b,   const float* __restrict__ zx_bn,
    const float* __restrict__ zxlw,   const float* __restrict__ zxlb,
    const float* __restrict__ zy_wih, const float* __restrict__ zy_whh,
    const float* __restrict__ zy_b,   const float* __restrict__ zy_bn,
    float* __restrict__ out_zx, float* __restrict__ out_h)
{
  const int b = blockIdx.x;
  const int tid = threadIdx.x;
  const int j = tid >> 1;
  const int half = tid & 1;

  __shared__ __align__(16) float s_h[Hh];
  __shared__ float s_i[H3];
  __shared__ float s_g[H3];
  __shared__ float s_x[17];
  __shared__ float s_bn[Hh];
  __shared__ float s_zxlwT[NZ*Hh];
  __shared__ float s_zxlb[NZ];
  __shared__ float s_zxh[Ll][NZ];

  // ================= PHASE A: zx encoder, 512 steps =================
  {
    float wi[17];
    #pragma unroll
    for (int c = 0; c < 17; c++) wi[c] = zx_wih[j*17 + c];
    const float bj = zx_b[j];
    float4 wr[16];
    {
      const float4* p = reinterpret_cast<const float4*>(zx_whh + (size_t)j*Hh + half*64);
      #pragma unroll
      for (int q = 0; q < 16; q++) wr[q] = p[q];
    }

    if (tid < Hh){ s_h[tid] = 0.0f; s_bn[tid] = zx_bn[tid]; }
    for (int q2 = tid; q2 < NZ*Hh; q2 += 768){
      int o = q2 >> 7, rem = q2 & 127, m = rem >> 3, q = rem & 7;
      s_zxlwT[q*128 + o*16 + m] = zxlw[q2];
    }
    if (tid < NZ) s_zxlb[tid] = zxlb[tid];

    float xreg = 0.f;
    if (tid < 17)
      xreg = (tid < 16) ? coeffs[(size_t)b*Tt*XC + tid] : tin[0];
    __syncthreads();

    for (int t = 0; t < Tt; t++){
      if (tid < 17) s_x[tid] = xreg;
      __syncthreads();
      float ai = bj;
      #pragma unroll
      for (int c = 0; c < 17; c++) ai += wi[c]*s_x[c];
      float g0=0.f, g1=0.f, g2=0.f, g3=0.f;
      {
        const float4* h4p = reinterpret_cast<const float4*>(&s_h[half*64]);
        #pragma unroll
        for (int q = 0; q < 16; q++){
          float4 w = wr[q];
          float4 h4 = h4p[q];
          g0 += w.x*h4.x; g1 += w.y*h4.y; g2 += w.z*h4.z; g3 += w.w*h4.w;
        }
      }
      float g = (g0+g1)+(g2+g3);
      g += __shfl_xor(g, 1, 64);
      if (half == 0){ s_i[j] = ai; s_g[j] = g; }
      if (tid < 17 && t + 1 < Tt){
        const int tn = t + 1;
        xreg = (tid < 16) ? coeffs[(size_t)b*Tt*XC + (size_t)tn*XC + tid] : tin[tn];
      }
      __syncthreads();
      if (tid < Hh){
        float r  = sigm_fast(s_i[tid]       + s_g[tid]);
        float zz = sigm_fast(s_i[Hh + tid]  + s_g[Hh + tid]);
        float n  = tanh_fast(s_i[2*Hh+tid] + r*(s_g[2*Hh+tid] + s_bn[tid]));
        s_h[tid] = n + zz*(s_h[tid] - n);
      }
      __syncthreads();
      if (tid < Hh){
        int m = tid & 15;
        const float4* hp = reinterpret_cast<const float4*>(&s_h[m*8]);
        float4 ha = hp[0], hb = hp[1];
        float p = s_zxlwT[0*128 + tid]*ha.x + s_zxlwT[1*128 + tid]*ha.y
                + s_zxlwT[2*128 + tid]*ha.z + s_zxlwT[3*128 + tid]*ha.w
                + s_zxlwT[4*128 + tid]*hb.x + s_zxlwT[5*128 + tid]*hb.y
                + s_zxlwT[6*128 + tid]*hb.z + s_zxlwT[7*128 + tid]*hb.w;
        p += __shfl_xor(p, 1, 64); p += __shfl_xor(p, 2, 64);
        p += __shfl_xor(p, 4, 64); p += __shfl_xor(p, 8, 64);
        if (m == 0){
          int o = tid >> 4;
          float val = s_zxlb[o] + p;
          if (t < Ll) s_zxh[t][o] = val;
          else out_zx[(size_t)b*Tt*NZ + (size_t)t*NZ + o] = val;
        }
      }
    }
  }
  __syncthreads();

  // ================= PHASE B: zy encoder, 256 steps =================
  {
    float wi[17];
    #pragma unroll
    for (int c = 0; c < 17; c++) wi[c] = zy_wih[j*17 + c];
    const float bj = zy_b[j];
    float4 wr[16];
    {
      const float4* p = reinterpret_cast<const float4*>(zy_whh + (size_t)j*Hh + half*64);
      #pragma unroll
      for (int q = 0; q < 16; q++) wr[q] = p[q];
    }
    if (tid < Hh){ s_h[tid] = 0.0f; s_bn[tid] = zy_bn[tid]; }

    float xreg = 0.f;
    if (tid < 8)        xreg = y_past[(size_t)b*Ll*NZ + tid];
    else if (tid == 16) xreg = tin[0];
    __syncthreads();

    for (int t = 0; t < Ll; t++){
      if (tid < 8)        s_x[tid] = xreg;
      else if (tid < 16)  s_x[tid] = s_zxh[t][tid - 8];
      else if (tid == 16) s_x[16] = xreg;
      __syncthreads();
      float ai = bj;
      #pragma unroll
      for (int c = 0; c < 17; c++) ai += wi[c]*s_x[c];
      float g0=0.f, g1=0.f, g2=0.f, g3=0.f;
      {
        const float4* h4p = reinterpret_cast<const float4*>(&s_h[half*64]);
        #pragma unroll
        for (int q = 0; q < 16; q++){
          float4 w = wr[q];
          float4 h4 = h4p[q];
          g0 += w.x*h4.x; g1 += w.y*h4.y; g2 += w.z*h4.z; g3 += w.w*h4.w;
        }
      }
      float g = (g0+g1)+(g2+g3);
      g += __shfl_xor(g, 1, 64);
      if (half == 0){ s_i[j] = ai; s_g[j] = g; }
      if (t + 1 < Ll){
        if (tid < 8)        xreg = y_past[(size_t)b*Ll*NZ + (size_t)(t+1)*NZ + tid];
        else if (tid == 16) xreg = tin[t+1];
      }
      __syncthreads();
      if (tid < Hh){
        float r  = sigm_fast(s_i[tid]       + s_g[tid]);
        float zz = sigm_fast(s_i[Hh + tid]  + s_g[Hh + tid]);
        float n  = tanh_fast(s_i[2*Hh+tid] + r*(s_g[2*Hh+tid] + s_bn[tid]));
        s_h[tid] = n + zz*(s_h[tid] - n);
      }
      __syncthreads();
    }
    if (tid < Hh) out_h[b*Hh + tid] = s_h[tid];
  }
}

// ---------------- CDE RK4 v14 — r18 shape + packed FMA + dX fold --------------
// 256 blocks (1/CU) x 2 batches x 512 threads (the allocator-safe config).
__global__ __launch_bounds__(512)
__attribute__((amdgpu_waves_per_eu(2, 2)))
void cde_fp32_kernel(
    const float* __restrict__ zy_h, const float* __restrict__ zx,
    const float* __restrict__ tin,
    const float* __restrict__ fw1, const float* __restrict__ fb1,
    const float* __restrict__ fw2, const float* __restrict__ fb2,
    const float* __restrict__ fw3, const float* __restrict__ fb3,
    const float* __restrict__ rw,  const float* __restrict__ rb,
    float* __restrict__ yout)
{
  const int tid = threadIdx.x;
  const int c12 = tid >> 2;      // G1/G2: output col 0..127
  const int q4  = tid & 3;       // G1/G2: k-quarter
  const int col64 = tid >> 3;    // G3: col-in-group 0..63
  const int e8    = tid & 7;     // G3: k-eighth (16 floats)
  const int bg = blockIdx.x * BBt;

  __shared__ __align__(16) float4 s_w1v[4096];   // 64 KB, [jj][col*4+q4]
  __shared__ __align__(16) float4 s_w2v[4096];   // 64 KB
  __shared__ __align__(16) float4 s_zinv[BBt][32];  // swizzled state rows
  __shared__ __align__(16) float4 s_h1v[BBt][32];
  __shared__ __align__(16) float4 s_h2v[BBt][32];
  __shared__ float s_o[BBt][W3N];                // raw pre-activations
  __shared__ float s_z[BBt][Hh];
  __shared__ float s_kacc[BBt][Hh];
  __shared__ float s_dx[BBt][CF];
  __shared__ float s_rw[OC*Hh];
  __shared__ float s_rb[OC];
  __shared__ float s_b3[W3N];

  float* zin_f0 = reinterpret_cast<float*>(&s_zinv[0][0]);
  float* zin_f1 = reinterpret_cast<float*>(&s_zinv[1][0]);
  float* h1_f0  = reinterpret_cast<float*>(&s_h1v[0][0]);
  float* h1_f1  = reinterpret_cast<float*>(&s_h1v[1][0]);
  float* h2_f0  = reinterpret_cast<float*>(&s_h2v[0][0]);
  float* h2_f1  = reinterpret_cast<float*>(&s_h2v[1][0]);

  // ---- one-time: w1/w2 -> [jj][col*4+q] layout; biases, readout, init ----
  for (int idx = tid; idx < Hh*32; idx += 512){
    int col = idx >> 5, jcol = idx & 31;
    int q = jcol >> 3, jj = jcol & 7;
    int dst = jj*512 + col*4 + q;
    s_w1v[dst] = reinterpret_cast<const float4*>(fw1)[idx];
    s_w2v[dst] = reinterpret_cast<const float4*>(fw2)[idx];
  }
  const float b1r = fb1[c12], b2r = fb2[c12];
  for (int idx = tid; idx < W3N; idx += 512) s_b3[idx] = fb3[idx];
  for (int idx = tid; idx < OC*Hh; idx += 512) s_rw[idx] = rw[idx];
  if (tid < OC) s_rb[tid] = rb[tid];
  if (tid < BBt*Hh){
    int b = tid >> 7, h = tid & 127;
    float zv = zy_h[(size_t)(bg + b)*Hh + h];
    s_z[b][h] = zv;
    (b == 0 ? zin_f0 : zin_f1)[swzf(h)] = zv;
  }
  __syncthreads();

  // y[:, 0, :]
  if (tid < 256){
    int b = tid >> 7, r = tid & 127, o = r >> 4, seg = r & 15;
    float p = 0.f;
    #pragma unroll
    for (int q = 0; q < 8; q++)
      p += s_z[b][seg*8 + q]*s_rw[o*Hh + seg*8 + q];
    p += __shfl_xor(p, 1, 64); p += __shfl_xor(p, 2, 64);
    p += __shfl_xor(p, 4, 64); p += __shfl_xor(p, 8, 64);
    if (seg == 0) yout[(size_t)(bg + b)*Ff*OC + o] = s_rb[o] + p;
  }

  const float* w3p = fw3 + (size_t)col64*Hh + e8*16;   // + g*8192 floats per iter

  for (int i = 0; i < Ff - 1; i++){
    for (int st = 0; st < 4; st++){
      // ---- issue w3 iters 0,1 now; latency hides under G1/G2 (2-deep only!) ----
      float4 A0, A1, A2, A3, B0, B1, B2, B3;
      {
        const float4* pA = reinterpret_cast<const float4*>(w3p);
        const float4* pB = reinterpret_cast<const float4*>(w3p + 8192);
        A0 = pA[0]; A1 = pA[1]; A2 = pA[2]; A3 = pA[3];
        B0 = pB[0]; B1 = pB[1]; B2 = pB[2]; B3 = pB[3];
      }
      // ---- dX fold (st==0 only): prev consumer was phase B of i-1, >=1 barrier ago
      if (st == 0 && tid < BBt*CF){
        int b = tid/CF, c = tid%CF;
        float d;
        if (c < 8){
          const float* zp = zx + (size_t)(bg + b)*Tt*NZ + (size_t)(Ll + i)*NZ + c;
          d = zp[NZ] - zp[0];
        } else {
          d = tin[Ll + i + 1] - tin[Ll + i];
        }
        s_dx[b][c] = d;
      }
      // ---- G1: h1 = softplus(zin @ w1.T + b1); packed FMA + DPP reduce ----
      {
        v2f a0 = {0.f, 0.f}, a1 = {0.f, 0.f};
        #pragma unroll
        for (int jj = 0; jj < 8; jj++){
          float4 z0 = s_zinv[0][swz32(q4*8 + jj)];
          float4 z1 = s_zinv[1][swz32(q4*8 + jj)];
          float4 w = s_w1v[jj*512 + tid];
          a0 = pk4(w, z0, a0); a1 = pk4(w, z1, a1);
        }
        float p0 = red4(a0.x + a0.y), p1 = red4(a1.x + a1.y);
        if (q4 == 0){
          h1_f0[swzf(c12)] = softplus_fast(b1r + p0);
          h1_f1[swzf(c12)] = softplus_fast(b1r + p1);
        }
      }
      __syncthreads();
      // ---- G2 ----
      {
        v2f a0 = {0.f, 0.f}, a1 = {0.f, 0.f};
        #pragma unroll
        for (int jj = 0; jj < 8; jj++){
          float4 z0 = s_h1v[0][swz32(q4*8 + jj)];
          float4 z1 = s_h1v[1][swz32(q4*8 + jj)];
          float4 w = s_w2v[jj*512 + tid];
          a0 = pk4(w, z0, a0); a1 = pk4(w, z1, a1);
        }
        float p0 = red4(a0.x + a0.y), p1 = red4(a1.x + a1.y);
        if (q4 == 0){
          h2_f0[swzf(c12)] = softplus_fast(b2r + p0);
          h2_f1[swzf(c12)] = softplus_fast(b2r + p1);
        }
      }
      __syncthreads();
      // ---- G3: 18 iters, 2-deep A/B pipeline, packed FMA, red8 ----
      {
        float4 h2a0 = s_h2v[0][swz32(e8*4 + 0)];
        float4 h2a1 = s_h2v[0][swz32(e8*4 + 1)];
        float4 h2a2 = s_h2v[0][swz32(e8*4 + 2)];
        float4 h2a3 = s_h2v[0][swz32(e8*4 + 3)];
        float4 h2b0 = s_h2v[1][swz32(e8*4 + 0)];
        float4 h2b1 = s_h2v[1][swz32(e8*4 + 1)];
        float4 h2b2 = s_h2v[1][swz32(e8*4 + 2)];
        float4 h2b3 = s_h2v[1][swz32(e8*4 + 3)];
        #pragma unroll 2
        for (int g = 0; g < 18; g++){
          float4 c0, c1, c2, c3;
          if ((g & 1) == 0){
            c0 = A0; c1 = A1; c2 = A2; c3 = A3;
            if (g + 2 < 18){
              const float4* pF = reinterpret_cast<const float4*>(w3p + (size_t)(g+2)*8192);
              A0 = pF[0]; A1 = pF[1]; A2 = pF[2]; A3 = pF[3];
            }
          } else {
            c0 = B0; c1 = B1; c2 = B2; c3 = B3;
            if (g + 2 < 18){
              const float4* pF = reinterpret_cast<const float4*>(w3p + (size_t)(g+2)*8192);
              B0 = pF[0]; B1 = pF[1]; B2 = pF[2]; B3 = pF[3];
            }
          }
          v2f a0 = {0.f, 0.f}, a1 = {0.f, 0.f};
          a0 = pk4(c0, h2a0, a0); a0 = pk4(c1, h2a1, a0);
          a0 = pk4(c2, h2a2, a0); a0 = pk4(c3, h2a3, a0);
          a1 = pk4(c0, h2b0, a1); a1 = pk4(c1, h2b1, a1);
          a1 = pk4(c2, h2b2, a1); a1 = pk4(c3, h2b3, a1);
          float p0 = red8(a0.x + a0.y), p1 = red8(a1.x + a1.y);
          if (e8 == 0){
            int n = g*64 + col64;
            s_o[0][n] = s_b3[n] + p0;
            s_o[1][n] = s_b3[n] + p1;
          }
        }
      }
      __syncthreads();
      // ---- phase B: 512 threads = 256 pairs x 2 halves; shfl(1) combine ----
      {
        int pr = tid >> 1, hf = tid & 1;
        int b = pr >> 7, h = pr & 127;
        const float* ob = &s_o[0][0] + b*W3N + h*CF;
        float kc = 0.f;
        #pragma unroll
        for (int jj = 0; jj < 4; jj++){
          int c = hf*4 + jj;
          kc += tanh_fast(ob[c]) * s_dx[b][c];
        }
        if (hf) kc += tanh_fast(ob[8]) * s_dx[b][8];
        kc += __shfl_xor(kc, 1, 64);
        if (hf == 0){
          float zv = s_z[b][h], zin;
          if      (st == 0){ s_kacc[b][h] = kc;        zin = zv + 0.5f*kc; }
          else if (st == 1){ s_kacc[b][h] += 2.f*kc;   zin = zv + 0.5f*kc; }
          else if (st == 2){ s_kacc[b][h] += 2.f*kc;   zin = zv + kc; }
          else { float zn = zv + (s_kacc[b][h] + kc)*(1.f/6.f); s_z[b][h] = zn; zin = zn; }
          (b == 0 ? zin_f0 : zin_f1)[swzf(h)] = zin;
        }
      }
      __syncthreads();
    }
    // readout y[:, i+1, :]
    if (tid < 256){
      int b = tid >> 7, r = tid & 127, o = r >> 4, seg = r & 15;
      float p = 0.f;
      #pragma unroll
      for (int q = 0; q < 8; q++)
        p += s_z[b][seg*8 + q]*s_rw[o*Hh + seg*8 + q];
      p += __shfl_xor(p, 1, 64); p += __shfl_xor(p, 2, 64);
      p += __shfl_xor(p, 4, 64); p += __shfl_xor(p, 8, 64);
      if (seg == 0) yout[(size_t)(bg + b)*Ff*OC + (size_t)(i + 1)*OC + o] = s_rb[o] + p;
    }
  }
}

extern "C" void kernel_launch(void* const* d_in, const int* in_sizes, int n_in,
                              void* d_out, int out_size, void* d_ws, size_t ws_size,
                              hipStream_t stream)
{
  (void)in_sizes; (void)n_in; (void)out_size; (void)ws_size;
  const float* y_past = (const float*)d_in[0];
  const float* t_in   = (const float*)d_in[1];
  const float* coeffs = (const float*)d_in[2];
  // d_in[3] = input_length (fixed 256)
  const float* zx_wih = (const float*)d_in[4];
  const float* zx_whh = (const float*)d_in[5];
  const float* zx_b   = (const float*)d_in[6];
  const float* zx_bn  = (const float*)d_in[7];
  const float* zxl_w  = (const float*)d_in[8];
  const float* zxl_b  = (const float*)d_in[9];
  const float* zy_wih = (const float*)d_in[10];
  const float* zy_whh = (const float*)d_in[11];
  const float* zy_b   = (const float*)d_in[12];
  const float* zy_bn  = (const float*)d_in[13];
  const float* fw1 = (const float*)d_in[14];
  const float* fb1 = (const float*)d_in[15];
  const float* fw2 = (const float*)d_in[16];
  const float* fb2 = (const float*)d_in[17];
  const float* fw3 = (const float*)d_in[18];
  const float* fb3 = (const float*)d_in[19];
  const float* r_w = (const float*)d_in[20];
  const float* r_b = (const float*)d_in[21];

  float* ws = (float*)d_ws;
  float* zx_buf = ws;                              // B*T*NZ fp32 = 8.39 MB
  float* zy_buf = ws + (size_t)Bb*Tt*NZ;           // B*H fp32   = 256 KB

  gru_fused_kernel<<<Bb, 768, 0, stream>>>(coeffs, y_past, t_in,
                                           zx_wih, zx_whh, zx_b, zx_bn,
                                           zxl_w, zxl_b,
                                           zy_wih, zy_whh, zy_b, zy_bn,
                                           zx_buf, zy_buf);
  cde_fp32_kernel<<<Bb/BBt, 512, 0, stream>>>(zy_buf, zx_buf, t_in,
                                              fw1, fb1, fw2, fb2, fw3, fb3,
                                              r_w, r_b, (float*)d_out);
}